// Round 1
// baseline (1058.702 us; speedup 1.0000x reference)
//
#include <hip/hip_runtime.h>
#include <hip/hip_bf16.h>

#define N_NODES 100000
#define N_EDGES 1600000
#define N_GRAPHS 2048
#define F0 128
#define F1 256
#define NCLS 64

// ---------------- CSR build ----------------

__global__ void count_deg(const int* __restrict__ dst, int* __restrict__ deg) {
    int e = blockIdx.x * blockDim.x + threadIdx.x;
    if (e < N_EDGES) {
        int d = dst[e];
        if ((unsigned)d < N_NODES) atomicAdd(&deg[d], 1);
    }
}

__global__ void count_batch(const int* __restrict__ batch, int* __restrict__ gcnt) {
    int i = blockIdx.x * blockDim.x + threadIdx.x;
    if (i < N_NODES) {
        int b = batch[i];
        if ((unsigned)b < N_GRAPHS) atomicAdd(&gcnt[b], 1);
    }
}

__global__ void compute_dinv(const int* __restrict__ deg, float* __restrict__ dinv) {
    int i = blockIdx.x * blockDim.x + threadIdx.x;
    if (i < N_NODES) dinv[i] = rsqrtf((float)(deg[i] + 1));  // +1 self loop, always >=1
}

// 3-phase exclusive-ish scan: out[0]=0, out[i+1]=inclusive prefix of in[0..i]
#define SCAN_B 1024

__global__ void scan_partial(const int* __restrict__ in, int n, int* __restrict__ bsum) {
    __shared__ int lds[SCAN_B];
    int i = blockIdx.x * SCAN_B + threadIdx.x;
    lds[threadIdx.x] = (i < n) ? in[i] : 0;
    __syncthreads();
    for (int s = SCAN_B / 2; s > 0; s >>= 1) {
        if (threadIdx.x < s) lds[threadIdx.x] += lds[threadIdx.x + s];
        __syncthreads();
    }
    if (threadIdx.x == 0) bsum[blockIdx.x] = lds[0];
}

__global__ void scan_bsum(int* __restrict__ bsum, int nb) {
    // single block, nb <= 1024; in-place exclusive scan
    __shared__ int lds[SCAN_B];
    int v = (threadIdx.x < nb) ? bsum[threadIdx.x] : 0;
    lds[threadIdx.x] = v;
    __syncthreads();
    for (int s = 1; s < SCAN_B; s <<= 1) {
        int t = (threadIdx.x >= s) ? lds[threadIdx.x - s] : 0;
        __syncthreads();
        lds[threadIdx.x] += t;
        __syncthreads();
    }
    if (threadIdx.x < nb) bsum[threadIdx.x] = lds[threadIdx.x] - v;  // exclusive
}

__global__ void scan_final(const int* __restrict__ in, int n, const int* __restrict__ bsum,
                           int* __restrict__ out) {
    __shared__ int lds[SCAN_B];
    int i = blockIdx.x * SCAN_B + threadIdx.x;
    int v = (i < n) ? in[i] : 0;
    lds[threadIdx.x] = v;
    __syncthreads();
    for (int s = 1; s < SCAN_B; s <<= 1) {
        int t = (threadIdx.x >= s) ? lds[threadIdx.x - s] : 0;
        __syncthreads();
        lds[threadIdx.x] += t;
        __syncthreads();
    }
    if (i < n) out[i + 1] = lds[threadIdx.x] + bsum[blockIdx.x];
    if (i == 0) out[0] = 0;
}

__global__ void copy_int(const int* __restrict__ a, int* __restrict__ b, int n) {
    int i = blockIdx.x * blockDim.x + threadIdx.x;
    if (i < n) b[i] = a[i];
}

__global__ void fill_csr(const int* __restrict__ src, const int* __restrict__ dst,
                         int* __restrict__ cursor, int* __restrict__ csr) {
    int e = blockIdx.x * blockDim.x + threadIdx.x;
    if (e < N_EDGES) {
        int d = dst[e];
        int s = src[e];
        if ((unsigned)d < N_NODES && (unsigned)s < N_NODES) {
            int p = atomicAdd(&cursor[d], 1);
            if ((unsigned)p < N_EDGES) csr[p] = s;
        }
    }
}

// ---------------- symmetric-norm aggregation (gather form) ----------------
// out[i] = dinv[i] * ( sum_{j in in(i)} h[j]*dinv[j]  +  h[i]*dinv[i] )

template <int F>
__global__ __launch_bounds__(256) void aggregate(const float* __restrict__ h,
                                                 const int* __restrict__ offs,
                                                 const int* __restrict__ csr,
                                                 const float* __restrict__ dinv,
                                                 float* __restrict__ out) {
    constexpr int V = F / 64;  // floats per lane: 2 (F=128) or 4 (F=256)
    int wave = blockIdx.x * (blockDim.x >> 6) + (threadIdx.x >> 6);
    if (wave >= N_NODES) return;
    int lane = threadIdx.x & 63;
    const int i = wave;
    float di = dinv[i];
    float acc[V];
    const float* hrow = h + (size_t)i * F + lane * V;
    if constexpr (V == 2) {
        float2 v = *(const float2*)hrow;
        acc[0] = v.x * di; acc[1] = v.y * di;
    } else {
        float4 v = *(const float4*)hrow;
        acc[0] = v.x * di; acc[1] = v.y * di; acc[2] = v.z * di; acc[3] = v.w * di;
    }
    int e0 = offs[i], e1 = offs[i + 1];
    for (int e = e0; e < e1; ++e) {
        int j = csr[e];
        float dj = dinv[j];
        const float* hj = h + (size_t)j * F + lane * V;
        if constexpr (V == 2) {
            float2 v = *(const float2*)hj;
            acc[0] += v.x * dj; acc[1] += v.y * dj;
        } else {
            float4 v = *(const float4*)hj;
            acc[0] += v.x * dj; acc[1] += v.y * dj; acc[2] += v.z * dj; acc[3] += v.w * dj;
        }
    }
    float* orow = out + (size_t)i * F + lane * V;
    if constexpr (V == 2) {
        *(float2*)orow = make_float2(acc[0] * di, acc[1] * di);
    } else {
        *(float4*)orow = make_float4(acc[0] * di, acc[1] * di, acc[2] * di, acc[3] * di);
    }
}

// ---------------- fp32 GEMM + bias + relu ----------------
// C[M,N] = relu(A[M,K] @ B[K,N] + bias[N]); N=256, M=100000, K in {128,256}

template <int K>
__global__ __launch_bounds__(256) void gemm_bias_relu(const float* __restrict__ A,
                                                      const float* __restrict__ B,
                                                      const float* __restrict__ bias,
                                                      float* __restrict__ C, int M, int N) {
    constexpr int BM = 128, BN = 128, BK = 16;
    __shared__ float As[BK][132];  // transposed A tile, padded
    __shared__ float Bs[BK][BN];
    int tid = threadIdx.x;
    int row0 = blockIdx.x * BM, col0 = blockIdx.y * BN;
    int tx = tid & 15, ty = tid >> 4;

    float acc[8][8];
#pragma unroll
    for (int i = 0; i < 8; ++i)
#pragma unroll
        for (int j = 0; j < 8; ++j) acc[i][j] = 0.f;

    int arow = tid >> 2;           // 0..63
    int ac = (tid & 3) * 4;        // 0,4,8,12
    int brow = tid >> 5;           // 0..7
    int bcol = (tid & 31) * 4;     // 0..124

    for (int k0 = 0; k0 < K; k0 += BK) {
#pragma unroll
        for (int p = 0; p < 2; ++p) {
            int r = arow + p * 64;
            int gr = row0 + r;
            float4 v = make_float4(0.f, 0.f, 0.f, 0.f);
            if (gr < M) v = *(const float4*)&A[(size_t)gr * K + k0 + ac];
            As[ac + 0][r] = v.x;
            As[ac + 1][r] = v.y;
            As[ac + 2][r] = v.z;
            As[ac + 3][r] = v.w;
        }
#pragma unroll
        for (int p = 0; p < 2; ++p) {
            int r = brow + p * 8;
            *(float4*)&Bs[r][bcol] = *(const float4*)&B[(size_t)(k0 + r) * N + col0 + bcol];
        }
        __syncthreads();
#pragma unroll
        for (int k = 0; k < BK; ++k) {
            float a[8], b[8];
#pragma unroll
            for (int i = 0; i < 8; ++i) a[i] = As[k][ty * 8 + i];
#pragma unroll
            for (int j = 0; j < 8; ++j) b[j] = Bs[k][tx * 8 + j];
#pragma unroll
            for (int i = 0; i < 8; ++i)
#pragma unroll
                for (int j = 0; j < 8; ++j) acc[i][j] += a[i] * b[j];
        }
        __syncthreads();
    }

#pragma unroll
    for (int i = 0; i < 8; ++i) {
        int gr = row0 + ty * 8 + i;
        if (gr >= M) continue;
#pragma unroll
        for (int j = 0; j < 8; j += 4) {
            int gc = col0 + tx * 8 + j;
            float4 o;
            o.x = fmaxf(acc[i][j + 0] + bias[gc + 0], 0.f);
            o.y = fmaxf(acc[i][j + 1] + bias[gc + 1], 0.f);
            o.z = fmaxf(acc[i][j + 2] + bias[gc + 2], 0.f);
            o.w = fmaxf(acc[i][j + 3] + bias[gc + 3], 0.f);
            *(float4*)&C[(size_t)gr * N + gc] = o;
        }
    }
}

// ---------------- mean pool over sorted batch ----------------

__global__ __launch_bounds__(256) void pool_kernel(const float* __restrict__ h2,
                                                   const int* __restrict__ goff,
                                                   float* __restrict__ g) {
    int gr = blockIdx.x;
    int t = threadIdx.x;
    int w = t >> 6, lane = t & 63;
    int c = lane * 4;
    int n0 = goff[gr], n1 = goff[gr + 1];
    float4 acc = make_float4(0.f, 0.f, 0.f, 0.f);
    for (int n = n0 + w; n < n1; n += 4) {
        const float4 v = *(const float4*)&h2[(size_t)n * F1 + c];
        acc.x += v.x; acc.y += v.y; acc.z += v.z; acc.w += v.w;
    }
    __shared__ float4 red[256];
    red[t] = acc;
    __syncthreads();
    if (w == 0) {
        float4 s = red[lane];
        for (int ww = 1; ww < 4; ++ww) {
            float4 v = red[ww * 64 + lane];
            s.x += v.x; s.y += v.y; s.z += v.z; s.w += v.w;
        }
        float inv = 1.f / fmaxf((float)(n1 - n0), 1.f);
        *(float4*)&g[(size_t)gr * F1 + c] = make_float4(s.x * inv, s.y * inv, s.z * inv, s.w * inv);
    }
}

// ---------------- classifier + log_softmax (one wave per graph) ----------------

__global__ void classify(const float* __restrict__ g, const float* __restrict__ Wc,
                         const float* __restrict__ bc, float* __restrict__ out) {
    int gr = blockIdx.x;
    int c = threadIdx.x;  // 0..63, single wave
    __shared__ float gl[F1];
    for (int k = c; k < F1; k += 64) gl[k] = g[(size_t)gr * F1 + k];
    __syncthreads();
    float acc = bc[c];
    for (int k = 0; k < F1; ++k) acc += gl[k] * Wc[k * NCLS + c];
    float m = acc;
    for (int s = 32; s > 0; s >>= 1) m = fmaxf(m, __shfl_xor(m, s, 64));
    float ex = __expf(acc - m);
    float sum = ex;
    for (int s = 32; s > 0; s >>= 1) sum += __shfl_xor(sum, s, 64);
    out[(size_t)gr * NCLS + c] = acc - m - __logf(sum);
}

// ---------------- launch ----------------

extern "C" void kernel_launch(void* const* d_in, const int* in_sizes, int n_in,
                              void* d_out, int out_size, void* d_ws, size_t ws_size,
                              hipStream_t stream) {
    const float* x = (const float*)d_in[0];
    const int* ei = (const int*)d_in[1];
    const int* batch = (const int*)d_in[2];
    const float* W1 = (const float*)d_in[3];
    const float* b1 = (const float*)d_in[4];
    const float* W2 = (const float*)d_in[5];
    const float* b2 = (const float*)d_in[6];
    const float* Wc = (const float*)d_in[7];
    const float* bc = (const float*)d_in[8];
    float* out = (float*)d_out;
    const int* src = ei;
    const int* dst = ei + N_EDGES;

    char* w = (char*)d_ws;
    auto take = [&](size_t n) { char* p = w; w += (n + 255) & ~(size_t)255; return p; };
    int* deg = (int*)take((size_t)N_NODES * 4);
    float* dinv = (float*)take((size_t)N_NODES * 4);
    int* offs = (int*)take((size_t)(N_NODES + 1) * 4);
    int* cursor = (int*)take((size_t)N_NODES * 4);
    int* bsum = (int*)take((size_t)1024 * 4);
    int* gcnt = (int*)take((size_t)N_GRAPHS * 4);
    int* goff = (int*)take((size_t)(N_GRAPHS + 1) * 4);
    int* csr = (int*)take((size_t)N_EDGES * 4);
    float* aggx = (float*)take((size_t)N_NODES * F0 * 4);
    float* h1 = (float*)take((size_t)N_NODES * F1 * 4);
    float* agg1 = (float*)take((size_t)N_NODES * F1 * 4);
    float* h2 = h1;  // h1 dead once agg1 is built; GEMM2 reads agg1, writes here
    float* gpool = (float*)take((size_t)N_GRAPHS * F1 * 4);

    hipMemsetAsync(deg, 0, (size_t)N_NODES * 4, stream);
    hipMemsetAsync(gcnt, 0, (size_t)N_GRAPHS * 4, stream);

    count_deg<<<(N_EDGES + 255) / 256, 256, 0, stream>>>(dst, deg);
    count_batch<<<(N_NODES + 255) / 256, 256, 0, stream>>>(batch, gcnt);
    compute_dinv<<<(N_NODES + 255) / 256, 256, 0, stream>>>(deg, dinv);

    int nb = (N_NODES + SCAN_B - 1) / SCAN_B;  // 98
    scan_partial<<<nb, SCAN_B, 0, stream>>>(deg, N_NODES, bsum);
    scan_bsum<<<1, SCAN_B, 0, stream>>>(bsum, nb);
    scan_final<<<nb, SCAN_B, 0, stream>>>(deg, N_NODES, bsum, offs);

    copy_int<<<(N_NODES + 255) / 256, 256, 0, stream>>>(offs, cursor, N_NODES);
    fill_csr<<<(N_EDGES + 255) / 256, 256, 0, stream>>>(src, dst, cursor, csr);

    int nb2 = (N_GRAPHS + SCAN_B - 1) / SCAN_B;  // 2
    scan_partial<<<nb2, SCAN_B, 0, stream>>>(gcnt, N_GRAPHS, bsum);
    scan_bsum<<<1, SCAN_B, 0, stream>>>(bsum, nb2);
    scan_final<<<nb2, SCAN_B, 0, stream>>>(gcnt, N_GRAPHS, bsum, goff);

    // conv1: aggregate x (128-d) first, then GEMM by W1 (+b1, relu)
    aggregate<F0><<<(N_NODES + 3) / 4, 256, 0, stream>>>(x, offs, csr, dinv, aggx);
    gemm_bias_relu<F0><<<dim3((N_NODES + 127) / 128, 2), 256, 0, stream>>>(aggx, W1, b1, h1, N_NODES, F1);

    // conv2: aggregate h1 (256-d), then GEMM by W2 (+b2, relu)
    aggregate<F1><<<(N_NODES + 3) / 4, 256, 0, stream>>>(h1, offs, csr, dinv, agg1);
    gemm_bias_relu<F1><<<dim3((N_NODES + 127) / 128, 2), 256, 0, stream>>>(agg1, W2, b2, h2, N_NODES, F1);

    // mean pool + classifier + log_softmax
    pool_kernel<<<N_GRAPHS, 256, 0, stream>>>(h2, goff, gpool);
    classify<<<N_GRAPHS, 64, 0, stream>>>(gpool, Wc, bc, out);
}

// Round 2
// 672.419 us; speedup vs baseline: 1.5745x; 1.5745x over previous
//
#include <hip/hip_runtime.h>
#include <hip/hip_bf16.h>

#define N_NODES 100000
#define N_EDGES 1600000
#define N_GRAPHS 2048
#define F0 128
#define F1 256
#define NCLS 64

typedef unsigned int uint32;
typedef unsigned short u16;
typedef u16 u16x8 __attribute__((ext_vector_type(8)));
typedef __bf16 bf16x8 __attribute__((ext_vector_type(8)));
typedef float f32x4 __attribute__((ext_vector_type(4)));

__device__ __forceinline__ float blo(uint32 v) { return __builtin_bit_cast(float, v << 16); }
__device__ __forceinline__ float bhi(uint32 v) { return __builtin_bit_cast(float, v & 0xffff0000u); }
__device__ __forceinline__ u16 f2bf(float f) {
    uint32 u = __builtin_bit_cast(uint32, f);
    u += 0x7fffu + ((u >> 16) & 1u);  // RNE
    return (u16)(u >> 16);
}
__device__ __forceinline__ uint32 pack2(float a, float b) {
    return (uint32)f2bf(a) | ((uint32)f2bf(b) << 16);
}

// ---------------- CSR build ----------------

__global__ void count_deg(const int* __restrict__ dst, int* __restrict__ deg) {
    int e = blockIdx.x * blockDim.x + threadIdx.x;
    if (e < N_EDGES) {
        int d = dst[e];
        if ((unsigned)d < N_NODES) atomicAdd(&deg[d], 1);
    }
}

__global__ void count_batch(const int* __restrict__ batch, int* __restrict__ gcnt) {
    int i = blockIdx.x * blockDim.x + threadIdx.x;
    if (i < N_NODES) {
        int b = batch[i];
        if ((unsigned)b < N_GRAPHS) atomicAdd(&gcnt[b], 1);
    }
}

__global__ void compute_dinv(const int* __restrict__ deg, float* __restrict__ dinv) {
    int i = blockIdx.x * blockDim.x + threadIdx.x;
    if (i < N_NODES) dinv[i] = rsqrtf((float)(deg[i] + 1));  // +1 self loop
}

#define SCAN_B 1024

__global__ void scan_partial(const int* __restrict__ in, int n, int* __restrict__ bsum) {
    __shared__ int lds[SCAN_B];
    int i = blockIdx.x * SCAN_B + threadIdx.x;
    lds[threadIdx.x] = (i < n) ? in[i] : 0;
    __syncthreads();
    for (int s = SCAN_B / 2; s > 0; s >>= 1) {
        if (threadIdx.x < s) lds[threadIdx.x] += lds[threadIdx.x + s];
        __syncthreads();
    }
    if (threadIdx.x == 0) bsum[blockIdx.x] = lds[0];
}

__global__ void scan_bsum(int* __restrict__ bsum, int nb) {
    __shared__ int lds[SCAN_B];
    int v = (threadIdx.x < nb) ? bsum[threadIdx.x] : 0;
    lds[threadIdx.x] = v;
    __syncthreads();
    for (int s = 1; s < SCAN_B; s <<= 1) {
        int t = (threadIdx.x >= s) ? lds[threadIdx.x - s] : 0;
        __syncthreads();
        lds[threadIdx.x] += t;
        __syncthreads();
    }
    if (threadIdx.x < nb) bsum[threadIdx.x] = lds[threadIdx.x] - v;  // exclusive
}

__global__ void scan_final(const int* __restrict__ in, int n, const int* __restrict__ bsum,
                           int* __restrict__ out) {
    __shared__ int lds[SCAN_B];
    int i = blockIdx.x * SCAN_B + threadIdx.x;
    int v = (i < n) ? in[i] : 0;
    lds[threadIdx.x] = v;
    __syncthreads();
    for (int s = 1; s < SCAN_B; s <<= 1) {
        int t = (threadIdx.x >= s) ? lds[threadIdx.x - s] : 0;
        __syncthreads();
        lds[threadIdx.x] += t;
        __syncthreads();
    }
    if (i < n) out[i + 1] = lds[threadIdx.x] + bsum[blockIdx.x];
    if (i == 0) out[0] = 0;
}

__global__ void copy_int(const int* __restrict__ a, int* __restrict__ b, int n) {
    int i = blockIdx.x * blockDim.x + threadIdx.x;
    if (i < n) b[i] = a[i];
}

__global__ void fill_csr(const int* __restrict__ src, const int* __restrict__ dst,
                         int* __restrict__ cursor, int* __restrict__ csr) {
    int e = blockIdx.x * blockDim.x + threadIdx.x;
    if (e < N_EDGES) {
        int d = dst[e];
        int s = src[e];
        if ((unsigned)d < N_NODES && (unsigned)s < N_NODES) {
            int p = atomicAdd(&cursor[d], 1);
            if ((unsigned)p < N_EDGES) csr[p] = s;
        }
    }
}

// ---------------- casts ----------------

// xs[i][:] = bf16( x[i][:] * dinv[i] )   (fold src-side norm into storage)
__global__ void cast_scale_x(const float* __restrict__ x, const float* __restrict__ dinv,
                             uint32* __restrict__ xs) {
    int idx = blockIdx.x * blockDim.x + threadIdx.x;  // one per 2 floats
    if (idx >= N_NODES * (F0 / 2)) return;
    int node = idx / (F0 / 2);
    float d = dinv[node];
    float2 v = *(const float2*)&x[(size_t)idx * 2];
    xs[idx] = pack2(v.x * d, v.y * d);
}

// Wt[n][k] = bf16(W[k][n])
__global__ void transpose_w(const float* __restrict__ W, u16* __restrict__ Wt, int K, int N) {
    int id = blockIdx.x * blockDim.x + threadIdx.x;
    if (id >= K * N) return;
    int k = id / N, n = id % N;
    Wt[(size_t)n * K + k] = f2bf(W[id]);
}

// ---------------- aggregation (gather form, pre-scaled rows) ----------------
// rows hs[j] are already h[j]*dinv[j]; out[i] = bf16( dinv[i] * (sum_j hs[j] + hs[i]) )

template <int F>
__global__ __launch_bounds__(256) void aggregate_bf(const u16* __restrict__ hs,
                                                    const int* __restrict__ offs,
                                                    const int* __restrict__ csr,
                                                    const float* __restrict__ dinv,
                                                    u16* __restrict__ out) {
    constexpr int V = F / 64;  // bf16 per lane: 2 (F=128) or 4 (F=256)
    int node = blockIdx.x * 4 + (threadIdx.x >> 6);
    if (node >= N_NODES) return;
    int lane = threadIdx.x & 63;
    const u16* selfp = hs + (size_t)node * F + lane * V;
    float acc[V];
    if constexpr (V == 2) {
        uint32 v = *(const uint32*)selfp;
        acc[0] = blo(v); acc[1] = bhi(v);
    } else {
        uint2 v = *(const uint2*)selfp;
        acc[0] = blo(v.x); acc[1] = bhi(v.x); acc[2] = blo(v.y); acc[3] = bhi(v.y);
    }
    int e0 = offs[node], e1 = offs[node + 1];
    int e = e0;
    // 2-deep pipeline: two row gathers in flight
    for (; e + 2 <= e1; e += 2) {
        int j0 = csr[e], j1 = csr[e + 1];
        const u16* p0 = hs + (size_t)j0 * F + lane * V;
        const u16* p1 = hs + (size_t)j1 * F + lane * V;
        if constexpr (V == 2) {
            uint32 a = *(const uint32*)p0;
            uint32 b = *(const uint32*)p1;
            acc[0] += blo(a) + blo(b);
            acc[1] += bhi(a) + bhi(b);
        } else {
            uint2 a = *(const uint2*)p0;
            uint2 b = *(const uint2*)p1;
            acc[0] += blo(a.x) + blo(b.x);
            acc[1] += bhi(a.x) + bhi(b.x);
            acc[2] += blo(a.y) + blo(b.y);
            acc[3] += bhi(a.y) + bhi(b.y);
        }
    }
    if (e < e1) {
        int j0 = csr[e];
        const u16* p0 = hs + (size_t)j0 * F + lane * V;
        if constexpr (V == 2) {
            uint32 a = *(const uint32*)p0;
            acc[0] += blo(a); acc[1] += bhi(a);
        } else {
            uint2 a = *(const uint2*)p0;
            acc[0] += blo(a.x); acc[1] += bhi(a.x);
            acc[2] += blo(a.y); acc[3] += bhi(a.y);
        }
    }
    float di = dinv[node];
    u16* orow = out + (size_t)node * F + lane * V;
    if constexpr (V == 2) {
        *(uint32*)orow = pack2(acc[0] * di, acc[1] * di);
    } else {
        uint2 o;
        o.x = pack2(acc[0] * di, acc[1] * di);
        o.y = pack2(acc[2] * di, acc[3] * di);
        *(uint2*)orow = o;
    }
}

// ---------------- bf16 MFMA GEMM + bias + relu (+ optional dinv row-scale) ----------------
// C[M,256] = relu(A[M,K] @ B[K,256] + bias) [* dinv[row]], A bf16 row-major, Bt = B^T bf16 [256][K]

template <int K, bool SCALE>
__global__ __launch_bounds__(256) void gemm_mfma(const u16* __restrict__ A,
                                                 const u16* __restrict__ Bt,
                                                 const float* __restrict__ bias,
                                                 const float* __restrict__ dinv,
                                                 u16* __restrict__ C, int M) {
    constexpr int BM = 128, BN = 128, BK = 64, BKP = 72;  // +8 bf16 pad keeps 16B align, spreads banks
    constexpr int NN = 256;
    __shared__ u16 As[BM][BKP];
    __shared__ u16 Bs[BN][BKP];
    int tid = threadIdx.x;
    int row0 = blockIdx.x * BM, col0 = blockIdx.y * BN;
    int lane = tid & 63, wid = tid >> 6;
    int wm = (wid >> 1) * 64, wn = (wid & 1) * 64;
    int lr = lane & 15, lq = lane >> 4;

    f32x4 acc[4][4];
#pragma unroll
    for (int i = 0; i < 4; ++i)
#pragma unroll
        for (int j = 0; j < 4; ++j) acc[i][j] = (f32x4){0.f, 0.f, 0.f, 0.f};

    for (int k0 = 0; k0 < K; k0 += BK) {
#pragma unroll
        for (int p = 0; p < 4; ++p) {
            int r = (tid >> 3) + p * 32;
            int c = (tid & 7) * 8;
            u16x8 av = {0, 0, 0, 0, 0, 0, 0, 0};
            int gr = row0 + r;
            if (gr < M) av = *(const u16x8*)&A[(size_t)gr * K + k0 + c];
            *(u16x8*)&As[r][c] = av;
            *(u16x8*)&Bs[r][c] = *(const u16x8*)&Bt[(size_t)(col0 + r) * K + k0 + c];
        }
        __syncthreads();
#pragma unroll
        for (int kk = 0; kk < BK; kk += 32) {
            bf16x8 af[4], bfr[4];
#pragma unroll
            for (int i = 0; i < 4; ++i)
                af[i] = __builtin_bit_cast(bf16x8, *(const u16x8*)&As[wm + i * 16 + lr][kk + lq * 8]);
#pragma unroll
            for (int j = 0; j < 4; ++j)
                bfr[j] = __builtin_bit_cast(bf16x8, *(const u16x8*)&Bs[wn + j * 16 + lr][kk + lq * 8]);
#pragma unroll
            for (int i = 0; i < 4; ++i)
#pragma unroll
                for (int j = 0; j < 4; ++j)
                    acc[i][j] = __builtin_amdgcn_mfma_f32_16x16x32_bf16(af[i], bfr[j], acc[i][j], 0, 0, 0);
        }
        __syncthreads();
    }

#pragma unroll
    for (int i = 0; i < 4; ++i) {
#pragma unroll
        for (int j = 0; j < 4; ++j) {
            int col = col0 + wn + j * 16 + lr;
            float bv = bias[col];
#pragma unroll
            for (int r = 0; r < 4; ++r) {
                int row = row0 + wm + i * 16 + lq * 4 + r;
                if (row < M) {
                    float v = fmaxf(acc[i][j][r] + bv, 0.f);
                    if constexpr (SCALE) v *= dinv[row];
                    C[(size_t)row * NN + col] = f2bf(v);
                }
            }
        }
    }
}

// ---------------- mean pool over sorted batch (bf16 in, fp32 out) ----------------

__global__ __launch_bounds__(256) void pool_kernel(const u16* __restrict__ h2,
                                                   const int* __restrict__ goff,
                                                   float* __restrict__ g) {
    int gr = blockIdx.x;
    int t = threadIdx.x;
    int w = t >> 6, lane = t & 63;
    int c = lane * 4;  // bf16 col base
    int n0 = goff[gr], n1 = goff[gr + 1];
    float4 acc = make_float4(0.f, 0.f, 0.f, 0.f);
    for (int n = n0 + w; n < n1; n += 4) {
        uint2 v = *(const uint2*)&h2[(size_t)n * F1 + c];
        acc.x += blo(v.x); acc.y += bhi(v.x); acc.z += blo(v.y); acc.w += bhi(v.y);
    }
    __shared__ float4 red[256];
    red[t] = acc;
    __syncthreads();
    if (w == 0) {
        float4 s = red[lane];
        for (int ww = 1; ww < 4; ++ww) {
            float4 v = red[ww * 64 + lane];
            s.x += v.x; s.y += v.y; s.z += v.z; s.w += v.w;
        }
        float inv = 1.f / fmaxf((float)(n1 - n0), 1.f);
        *(float4*)&g[(size_t)gr * F1 + c] = make_float4(s.x * inv, s.y * inv, s.z * inv, s.w * inv);
    }
}

// ---------------- classifier + log_softmax (one wave per graph) ----------------

__global__ void classify(const float* __restrict__ g, const float* __restrict__ Wc,
                         const float* __restrict__ bc, float* __restrict__ out) {
    int gr = blockIdx.x;
    int c = threadIdx.x;  // 0..63, single wave
    __shared__ float gl[F1];
    for (int k = c; k < F1; k += 64) gl[k] = g[(size_t)gr * F1 + k];
    __syncthreads();
    float acc = bc[c];
    for (int k = 0; k < F1; ++k) acc += gl[k] * Wc[k * NCLS + c];
    float m = acc;
    for (int s = 32; s > 0; s >>= 1) m = fmaxf(m, __shfl_xor(m, s, 64));
    float ex = __expf(acc - m);
    float sum = ex;
    for (int s = 32; s > 0; s >>= 1) sum += __shfl_xor(sum, s, 64);
    out[(size_t)gr * NCLS + c] = acc - m - __logf(sum);
}

// ---------------- launch ----------------

extern "C" void kernel_launch(void* const* d_in, const int* in_sizes, int n_in,
                              void* d_out, int out_size, void* d_ws, size_t ws_size,
                              hipStream_t stream) {
    const float* x = (const float*)d_in[0];
    const int* ei = (const int*)d_in[1];
    const int* batch = (const int*)d_in[2];
    const float* W1 = (const float*)d_in[3];
    const float* b1 = (const float*)d_in[4];
    const float* W2 = (const float*)d_in[5];
    const float* b2 = (const float*)d_in[6];
    const float* Wc = (const float*)d_in[7];
    const float* bc = (const float*)d_in[8];
    float* out = (float*)d_out;
    const int* src = ei;
    const int* dst = ei + N_EDGES;

    char* w = (char*)d_ws;
    auto take = [&](size_t n) { char* p = w; w += (n + 255) & ~(size_t)255; return p; };
    int* deg = (int*)take((size_t)N_NODES * 4);
    float* dinv = (float*)take((size_t)N_NODES * 4);
    int* offs = (int*)take((size_t)(N_NODES + 1) * 4);
    int* cursor = (int*)take((size_t)N_NODES * 4);
    int* bsum = (int*)take((size_t)1024 * 4);
    int* gcnt = (int*)take((size_t)N_GRAPHS * 4);
    int* goff = (int*)take((size_t)(N_GRAPHS + 1) * 4);
    int* csr = (int*)take((size_t)N_EDGES * 4);
    uint32* xs = (uint32*)take((size_t)N_NODES * F0 * 2);       // bf16, dinv-scaled
    u16* aggx = (u16*)take((size_t)N_NODES * F0 * 2);           // bf16
    u16* hs1 = (u16*)take((size_t)N_NODES * F1 * 2);            // bf16, dinv-scaled
    u16* agg1 = (u16*)take((size_t)N_NODES * F1 * 2);           // bf16
    u16* h2 = (u16*)take((size_t)N_NODES * F1 * 2);             // bf16, unscaled
    u16* W1t = (u16*)take((size_t)F0 * F1 * 2);
    u16* W2t = (u16*)take((size_t)F1 * F1 * 2);
    float* gpool = (float*)take((size_t)N_GRAPHS * F1 * 4);

    hipMemsetAsync(deg, 0, (size_t)N_NODES * 4, stream);
    hipMemsetAsync(gcnt, 0, (size_t)N_GRAPHS * 4, stream);

    count_deg<<<(N_EDGES + 255) / 256, 256, 0, stream>>>(dst, deg);
    count_batch<<<(N_NODES + 255) / 256, 256, 0, stream>>>(batch, gcnt);
    compute_dinv<<<(N_NODES + 255) / 256, 256, 0, stream>>>(deg, dinv);

    int nb = (N_NODES + SCAN_B - 1) / SCAN_B;  // 98
    scan_partial<<<nb, SCAN_B, 0, stream>>>(deg, N_NODES, bsum);
    scan_bsum<<<1, SCAN_B, 0, stream>>>(bsum, nb);
    scan_final<<<nb, SCAN_B, 0, stream>>>(deg, N_NODES, bsum, offs);

    copy_int<<<(N_NODES + 255) / 256, 256, 0, stream>>>(offs, cursor, N_NODES);
    fill_csr<<<(N_EDGES + 255) / 256, 256, 0, stream>>>(src, dst, cursor, csr);

    int nb2 = (N_GRAPHS + SCAN_B - 1) / SCAN_B;  // 2
    scan_partial<<<nb2, SCAN_B, 0, stream>>>(gcnt, N_GRAPHS, bsum);
    scan_bsum<<<1, SCAN_B, 0, stream>>>(bsum, nb2);
    scan_final<<<nb2, SCAN_B, 0, stream>>>(gcnt, N_GRAPHS, bsum, goff);

    // weight prep + x cast (scaled by dinv)
    transpose_w<<<(F0 * F1 + 255) / 256, 256, 0, stream>>>(W1, W1t, F0, F1);
    transpose_w<<<(F1 * F1 + 255) / 256, 256, 0, stream>>>(W2, W2t, F1, F1);
    cast_scale_x<<<(N_NODES * (F0 / 2) + 255) / 256, 256, 0, stream>>>(x, dinv, xs);

    // conv1: aggregate xs (128-d bf16), then MFMA GEMM by W1 (+b1, relu, *dinv for next layer)
    aggregate_bf<F0><<<(N_NODES + 3) / 4, 256, 0, stream>>>((const u16*)xs, offs, csr, dinv, aggx);
    gemm_mfma<F0, true><<<dim3((N_NODES + 127) / 128, 2), 256, 0, stream>>>(aggx, W1t, b1, dinv, hs1, N_NODES);

    // conv2: aggregate hs1 (256-d bf16), then MFMA GEMM by W2 (+b2, relu, unscaled)
    aggregate_bf<F1><<<(N_NODES + 3) / 4, 256, 0, stream>>>(hs1, offs, csr, dinv, agg1);
    gemm_mfma<F1, false><<<dim3((N_NODES + 127) / 128, 2), 256, 0, stream>>>(agg1, W2t, b2, dinv, h2, N_NODES);

    // mean pool + classifier + log_softmax
    pool_kernel<<<N_GRAPHS, 256, 0, stream>>>(h2, goff, gpool);
    classify<<<N_GRAPHS, 64, 0, stream>>>(gpool, Wc, bc, out);
}

// Round 3
// 549.634 us; speedup vs baseline: 1.9262x; 1.2234x over previous
//
#include <hip/hip_runtime.h>
#include <hip/hip_bf16.h>

#define N_NODES 100000
#define N_EDGES 1600000
#define N_GRAPHS 2048
#define F0 128
#define F1 256
#define NCLS 64

// bucketed CSR build
#define BSHIFT 9
#define BNODES 512                      // nodes per bucket = 1<<BSHIFT
#define NB 196                          // ceil(N_NODES/BNODES)
#define EPB 4096                        // edges per chunk-block
#define NCHUNK 391                      // ceil(N_EDGES/EPB)
#define FLATN (NB * NCHUNK)             // 76636

typedef unsigned int uint32;
typedef unsigned short u16;
typedef u16 u16x8 __attribute__((ext_vector_type(8)));
typedef __bf16 bf16x8 __attribute__((ext_vector_type(8)));
typedef float f32x4 __attribute__((ext_vector_type(4)));

__device__ __forceinline__ float blo(uint32 v) { return __builtin_bit_cast(float, v << 16); }
__device__ __forceinline__ float bhi(uint32 v) { return __builtin_bit_cast(float, v & 0xffff0000u); }
__device__ __forceinline__ u16 f2bf(float f) {
    uint32 u = __builtin_bit_cast(uint32, f);
    u += 0x7fffu + ((u >> 16) & 1u);  // RNE
    return (u16)(u >> 16);
}
__device__ __forceinline__ uint32 pack2(float a, float b) {
    return (uint32)f2bf(a) | ((uint32)f2bf(b) << 16);
}

// ---------------- generic scans (3-phase) ----------------
#define SCAN_B 1024

__global__ void scan_partial(const int* __restrict__ in, int n, int* __restrict__ bsum) {
    __shared__ int lds[SCAN_B];
    int i = blockIdx.x * SCAN_B + threadIdx.x;
    lds[threadIdx.x] = (i < n) ? in[i] : 0;
    __syncthreads();
    for (int s = SCAN_B / 2; s > 0; s >>= 1) {
        if (threadIdx.x < s) lds[threadIdx.x] += lds[threadIdx.x + s];
        __syncthreads();
    }
    if (threadIdx.x == 0) bsum[blockIdx.x] = lds[0];
}

__global__ void scan_bsum(int* __restrict__ bsum, int nb) {
    __shared__ int lds[SCAN_B];
    int v = (threadIdx.x < nb) ? bsum[threadIdx.x] : 0;
    lds[threadIdx.x] = v;
    __syncthreads();
    for (int s = 1; s < SCAN_B; s <<= 1) {
        int t = (threadIdx.x >= s) ? lds[threadIdx.x - s] : 0;
        __syncthreads();
        lds[threadIdx.x] += t;
        __syncthreads();
    }
    if (threadIdx.x < nb) bsum[threadIdx.x] = lds[threadIdx.x] - v;  // exclusive
}

__global__ void scan_final(const int* __restrict__ in, int n, const int* __restrict__ bsum,
                           int* __restrict__ out) {
    __shared__ int lds[SCAN_B];
    int i = blockIdx.x * SCAN_B + threadIdx.x;
    int v = (i < n) ? in[i] : 0;
    lds[threadIdx.x] = v;
    __syncthreads();
    for (int s = 1; s < SCAN_B; s <<= 1) {
        int t = (threadIdx.x >= s) ? lds[threadIdx.x - s] : 0;
        __syncthreads();
        lds[threadIdx.x] += t;
        __syncthreads();
    }
    if (i < n) out[i + 1] = lds[threadIdx.x] + bsum[blockIdx.x];
    if (i == 0) out[0] = 0;
}

// ---------------- bucketed CSR build ----------------

// Pass A: per-chunk bucket histogram. hist[b*NCHUNK + chunk]
__global__ __launch_bounds__(256) void hist_pass(const int* __restrict__ dst,
                                                 int* __restrict__ hist) {
    __shared__ int lh[NB];
    int t = threadIdx.x, blk = blockIdx.x;
    if (t < NB) lh[t] = 0;
    __syncthreads();
#pragma unroll
    for (int k = 0; k < EPB / 256; ++k) {
        int e = blk * EPB + k * 256 + t;
        if (e < N_EDGES) atomicAdd(&lh[dst[e] >> BSHIFT], 1);
    }
    __syncthreads();
    if (t < NB) hist[t * NCHUNK + blk] = lh[t];
}

// Pass C: bin (dst,src) pairs into bucket regions at block-private offsets.
__global__ __launch_bounds__(256) void bin_pairs(const int* __restrict__ src,
                                                 const int* __restrict__ dst,
                                                 const int* __restrict__ histoff,
                                                 uint2* __restrict__ pairs) {
    __shared__ int lbase[NB];
    __shared__ int lcur[NB];
    int t = threadIdx.x, blk = blockIdx.x;
    if (t < NB) {
        lbase[t] = histoff[t * NCHUNK + blk];
        lcur[t] = 0;
    }
    __syncthreads();
#pragma unroll
    for (int k = 0; k < EPB / 256; ++k) {
        int e = blk * EPB + k * 256 + t;
        if (e < N_EDGES) {
            int d = dst[e], s = src[e];
            int b = d >> BSHIFT;
            int r = atomicAdd(&lcur[b], 1);
            pairs[lbase[b] + r] = make_uint2((unsigned)d, (unsigned)s);
        }
    }
}

// Pass D: per-bucket CSR finalize. One block per bucket.
// Computes deg->dinv, offs (coalesced), csr (block-private region).
__global__ __launch_bounds__(256) void bucket_csr(const uint2* __restrict__ pairs,
                                                  const int* __restrict__ histoff,
                                                  int* __restrict__ offs,
                                                  int* __restrict__ csr,
                                                  float* __restrict__ dinv) {
    __shared__ int lcnt[BNODES];
    __shared__ int lcur[BNODES];
    __shared__ int psum[256];
    int t = threadIdx.x, b = blockIdx.x;
    int n0 = b << BSHIFT;
    int nn = min(BNODES, N_NODES - n0);
    lcnt[t] = 0;
    lcnt[t + 256] = 0;
    __syncthreads();
    int ebase = histoff[b * NCHUNK];
    int eend = (b == NB - 1) ? N_EDGES : histoff[(b + 1) * NCHUNK];
    for (int i = ebase + t; i < eend; i += 256) {
        atomicAdd(&lcnt[(int)pairs[i].x - n0], 1);
    }
    __syncthreads();
    // dinv
    int c0 = lcnt[2 * t], c1 = lcnt[2 * t + 1];
    if (2 * t < nn) dinv[n0 + 2 * t] = rsqrtf((float)(c0 + 1));
    if (2 * t + 1 < nn) dinv[n0 + 2 * t + 1] = rsqrtf((float)(c1 + 1));
    // scan 512 via pair-sums + Hillis-Steele over 256
    psum[t] = c0 + c1;
    __syncthreads();
    for (int s = 1; s < 256; s <<= 1) {
        int v = (t >= s) ? psum[t - s] : 0;
        __syncthreads();
        psum[t] += v;
        __syncthreads();
    }
    int ep = psum[t] - (c0 + c1);  // exclusive over pairs
    lcur[2 * t] = ep;
    lcur[2 * t + 1] = ep + c0;
    if (2 * t < nn) offs[n0 + 2 * t] = ebase + ep;
    if (2 * t + 1 < nn) offs[n0 + 2 * t + 1] = ebase + ep + c0;
    if (b == NB - 1 && t == 0) offs[N_NODES] = N_EDGES;
    __syncthreads();
    for (int i = ebase + t; i < eend; i += 256) {
        uint2 p = pairs[i];
        int r = atomicAdd(&lcur[(int)p.x - n0], 1);
        csr[ebase + r] = (int)p.y;
    }
}

// ---------------- batch histogram ----------------

__global__ void count_batch(const int* __restrict__ batch, int* __restrict__ gcnt) {
    int i = blockIdx.x * blockDim.x + threadIdx.x;
    if (i < N_NODES) {
        int b = batch[i];
        if ((unsigned)b < N_GRAPHS) atomicAdd(&gcnt[b], 1);
    }
}

// ---------------- casts ----------------

__global__ void cast_scale_x(const float* __restrict__ x, const float* __restrict__ dinv,
                             uint32* __restrict__ xs) {
    int idx = blockIdx.x * blockDim.x + threadIdx.x;  // one per 2 floats
    if (idx >= N_NODES * (F0 / 2)) return;
    int node = idx / (F0 / 2);
    float d = dinv[node];
    float2 v = *(const float2*)&x[(size_t)idx * 2];
    xs[idx] = pack2(v.x * d, v.y * d);
}

__global__ void transpose_w(const float* __restrict__ W, u16* __restrict__ Wt, int K, int N) {
    int id = blockIdx.x * blockDim.x + threadIdx.x;
    if (id >= K * N) return;
    int k = id / N, n = id % N;
    Wt[(size_t)n * K + k] = f2bf(W[id]);
}

// ---------------- aggregation (gather form, pre-scaled rows) ----------------

template <int F>
__global__ __launch_bounds__(256) void aggregate_bf(const u16* __restrict__ hs,
                                                    const int* __restrict__ offs,
                                                    const int* __restrict__ csr,
                                                    const float* __restrict__ dinv,
                                                    u16* __restrict__ out) {
    constexpr int V = F / 64;
    int node = blockIdx.x * 4 + (threadIdx.x >> 6);
    if (node >= N_NODES) return;
    int lane = threadIdx.x & 63;
    const u16* selfp = hs + (size_t)node * F + lane * V;
    float acc[V];
    if constexpr (V == 2) {
        uint32 v = *(const uint32*)selfp;
        acc[0] = blo(v); acc[1] = bhi(v);
    } else {
        uint2 v = *(const uint2*)selfp;
        acc[0] = blo(v.x); acc[1] = bhi(v.x); acc[2] = blo(v.y); acc[3] = bhi(v.y);
    }
    int e0 = offs[node], e1 = offs[node + 1];
    int e = e0;
    for (; e + 2 <= e1; e += 2) {
        int j0 = csr[e], j1 = csr[e + 1];
        const u16* p0 = hs + (size_t)j0 * F + lane * V;
        const u16* p1 = hs + (size_t)j1 * F + lane * V;
        if constexpr (V == 2) {
            uint32 a = *(const uint32*)p0;
            uint32 b = *(const uint32*)p1;
            acc[0] += blo(a) + blo(b);
            acc[1] += bhi(a) + bhi(b);
        } else {
            uint2 a = *(const uint2*)p0;
            uint2 b = *(const uint2*)p1;
            acc[0] += blo(a.x) + blo(b.x);
            acc[1] += bhi(a.x) + bhi(b.x);
            acc[2] += blo(a.y) + blo(b.y);
            acc[3] += bhi(a.y) + bhi(b.y);
        }
    }
    if (e < e1) {
        int j0 = csr[e];
        const u16* p0 = hs + (size_t)j0 * F + lane * V;
        if constexpr (V == 2) {
            uint32 a = *(const uint32*)p0;
            acc[0] += blo(a); acc[1] += bhi(a);
        } else {
            uint2 a = *(const uint2*)p0;
            acc[0] += blo(a.x); acc[1] += bhi(a.x);
            acc[2] += blo(a.y); acc[3] += bhi(a.y);
        }
    }
    float di = dinv[node];
    u16* orow = out + (size_t)node * F + lane * V;
    if constexpr (V == 2) {
        *(uint32*)orow = pack2(acc[0] * di, acc[1] * di);
    } else {
        uint2 o;
        o.x = pack2(acc[0] * di, acc[1] * di);
        o.y = pack2(acc[2] * di, acc[3] * di);
        *(uint2*)orow = o;
    }
}

// ---------------- bf16 MFMA GEMM + bias + relu (+ optional dinv row-scale) ----------------

template <int K, bool SCALE>
__global__ __launch_bounds__(256) void gemm_mfma(const u16* __restrict__ A,
                                                 const u16* __restrict__ Bt,
                                                 const float* __restrict__ bias,
                                                 const float* __restrict__ dinv,
                                                 u16* __restrict__ C, int M) {
    constexpr int BM = 128, BN = 128, BK = 64, BKP = 72;
    constexpr int NN = 256;
    __shared__ u16 As[BM][BKP];
    __shared__ u16 Bs[BN][BKP];
    int tid = threadIdx.x;
    int row0 = blockIdx.x * BM, col0 = blockIdx.y * BN;
    int lane = tid & 63, wid = tid >> 6;
    int wm = (wid >> 1) * 64, wn = (wid & 1) * 64;
    int lr = lane & 15, lq = lane >> 4;

    f32x4 acc[4][4];
#pragma unroll
    for (int i = 0; i < 4; ++i)
#pragma unroll
        for (int j = 0; j < 4; ++j) acc[i][j] = (f32x4){0.f, 0.f, 0.f, 0.f};

    for (int k0 = 0; k0 < K; k0 += BK) {
#pragma unroll
        for (int p = 0; p < 4; ++p) {
            int r = (tid >> 3) + p * 32;
            int c = (tid & 7) * 8;
            u16x8 av = {0, 0, 0, 0, 0, 0, 0, 0};
            int gr = row0 + r;
            if (gr < M) av = *(const u16x8*)&A[(size_t)gr * K + k0 + c];
            *(u16x8*)&As[r][c] = av;
            *(u16x8*)&Bs[r][c] = *(const u16x8*)&Bt[(size_t)(col0 + r) * K + k0 + c];
        }
        __syncthreads();
#pragma unroll
        for (int kk = 0; kk < BK; kk += 32) {
            bf16x8 af[4], bfr[4];
#pragma unroll
            for (int i = 0; i < 4; ++i)
                af[i] = __builtin_bit_cast(bf16x8, *(const u16x8*)&As[wm + i * 16 + lr][kk + lq * 8]);
#pragma unroll
            for (int j = 0; j < 4; ++j)
                bfr[j] = __builtin_bit_cast(bf16x8, *(const u16x8*)&Bs[wn + j * 16 + lr][kk + lq * 8]);
#pragma unroll
            for (int i = 0; i < 4; ++i)
#pragma unroll
                for (int j = 0; j < 4; ++j)
                    acc[i][j] = __builtin_amdgcn_mfma_f32_16x16x32_bf16(af[i], bfr[j], acc[i][j], 0, 0, 0);
        }
        __syncthreads();
    }

#pragma unroll
    for (int i = 0; i < 4; ++i) {
#pragma unroll
        for (int j = 0; j < 4; ++j) {
            int col = col0 + wn + j * 16 + lr;
            float bv = bias[col];
#pragma unroll
            for (int r = 0; r < 4; ++r) {
                int row = row0 + wm + i * 16 + lq * 4 + r;
                if (row < M) {
                    float v = fmaxf(acc[i][j][r] + bv, 0.f);
                    if constexpr (SCALE) v *= dinv[row];
                    C[(size_t)row * NN + col] = f2bf(v);
                }
            }
        }
    }
}

// ---------------- mean pool over sorted batch (bf16 in, fp32 out) ----------------

__global__ __launch_bounds__(256) void pool_kernel(const u16* __restrict__ h2,
                                                   const int* __restrict__ goff,
                                                   float* __restrict__ g) {
    int gr = blockIdx.x;
    int t = threadIdx.x;
    int w = t >> 6, lane = t & 63;
    int c = lane * 4;
    int n0 = goff[gr], n1 = goff[gr + 1];
    float4 acc = make_float4(0.f, 0.f, 0.f, 0.f);
    for (int n = n0 + w; n < n1; n += 4) {
        uint2 v = *(const uint2*)&h2[(size_t)n * F1 + c];
        acc.x += blo(v.x); acc.y += bhi(v.x); acc.z += blo(v.y); acc.w += bhi(v.y);
    }
    __shared__ float4 red[256];
    red[t] = acc;
    __syncthreads();
    if (w == 0) {
        float4 s = red[lane];
        for (int ww = 1; ww < 4; ++ww) {
            float4 v = red[ww * 64 + lane];
            s.x += v.x; s.y += v.y; s.z += v.z; s.w += v.w;
        }
        float inv = 1.f / fmaxf((float)(n1 - n0), 1.f);
        *(float4*)&g[(size_t)gr * F1 + c] = make_float4(s.x * inv, s.y * inv, s.z * inv, s.w * inv);
    }
}

// ---------------- classifier + log_softmax ----------------

__global__ void classify(const float* __restrict__ g, const float* __restrict__ Wc,
                         const float* __restrict__ bc, float* __restrict__ out) {
    int gr = blockIdx.x;
    int c = threadIdx.x;  // 0..63, single wave
    __shared__ float gl[F1];
    for (int k = c; k < F1; k += 64) gl[k] = g[(size_t)gr * F1 + k];
    __syncthreads();
    float acc = bc[c];
    for (int k = 0; k < F1; ++k) acc += gl[k] * Wc[k * NCLS + c];
    float m = acc;
    for (int s = 32; s > 0; s >>= 1) m = fmaxf(m, __shfl_xor(m, s, 64));
    float ex = __expf(acc - m);
    float sum = ex;
    for (int s = 32; s > 0; s >>= 1) sum += __shfl_xor(sum, s, 64);
    out[(size_t)gr * NCLS + c] = acc - m - __logf(sum);
}

// ---------------- launch ----------------

extern "C" void kernel_launch(void* const* d_in, const int* in_sizes, int n_in,
                              void* d_out, int out_size, void* d_ws, size_t ws_size,
                              hipStream_t stream) {
    const float* x = (const float*)d_in[0];
    const int* ei = (const int*)d_in[1];
    const int* batch = (const int*)d_in[2];
    const float* W1 = (const float*)d_in[3];
    const float* b1 = (const float*)d_in[4];
    const float* W2 = (const float*)d_in[5];
    const float* b2 = (const float*)d_in[6];
    const float* Wc = (const float*)d_in[7];
    const float* bc = (const float*)d_in[8];
    float* out = (float*)d_out;
    const int* src = ei;
    const int* dst = ei + N_EDGES;

    char* w = (char*)d_ws;
    auto take = [&](size_t n) { char* p = w; w += (n + 255) & ~(size_t)255; return p; };
    float* dinv = (float*)take((size_t)N_NODES * 4);
    int* offs = (int*)take((size_t)(N_NODES + 1) * 4);
    int* hist = (int*)take((size_t)FLATN * 4);
    int* histoff = (int*)take((size_t)(FLATN + 1) * 4);
    int* bsum = (int*)take((size_t)1024 * 4);
    int* gcnt = (int*)take((size_t)N_GRAPHS * 4);
    int* goff = (int*)take((size_t)(N_GRAPHS + 1) * 4);
    uint2* pairs = (uint2*)take((size_t)N_EDGES * 8);
    int* csr = (int*)take((size_t)N_EDGES * 4);
    uint32* xs = (uint32*)take((size_t)N_NODES * F0 * 2);
    u16* aggx = (u16*)take((size_t)N_NODES * F0 * 2);
    u16* hs1 = (u16*)take((size_t)N_NODES * F1 * 2);
    u16* agg1 = (u16*)take((size_t)N_NODES * F1 * 2);
    u16* h2 = (u16*)take((size_t)N_NODES * F1 * 2);
    u16* W1t = (u16*)take((size_t)F0 * F1 * 2);
    u16* W2t = (u16*)take((size_t)F1 * F1 * 2);
    float* gpool = (float*)take((size_t)N_GRAPHS * F1 * 4);

    hipMemsetAsync(gcnt, 0, (size_t)N_GRAPHS * 4, stream);

    // CSR build: hist -> scan -> bin -> per-bucket finalize (deg/dinv/offs/csr)
    hist_pass<<<NCHUNK, 256, 0, stream>>>(dst, hist);
    {
        int nb = (FLATN + SCAN_B - 1) / SCAN_B;  // 75
        scan_partial<<<nb, SCAN_B, 0, stream>>>(hist, FLATN, bsum);
        scan_bsum<<<1, SCAN_B, 0, stream>>>(bsum, nb);
        scan_final<<<nb, SCAN_B, 0, stream>>>(hist, FLATN, bsum, histoff);
    }
    bin_pairs<<<NCHUNK, 256, 0, stream>>>(src, dst, histoff, pairs);
    bucket_csr<<<NB, 256, 0, stream>>>(pairs, histoff, offs, csr, dinv);

    // batch -> graph offsets
    count_batch<<<(N_NODES + 255) / 256, 256, 0, stream>>>(batch, gcnt);
    {
        int nb2 = (N_GRAPHS + SCAN_B - 1) / SCAN_B;  // 2
        scan_partial<<<nb2, SCAN_B, 0, stream>>>(gcnt, N_GRAPHS, bsum);
        scan_bsum<<<1, SCAN_B, 0, stream>>>(bsum, nb2);
        scan_final<<<nb2, SCAN_B, 0, stream>>>(gcnt, N_GRAPHS, bsum, goff);
    }

    // weight prep + x cast (scaled by dinv)
    transpose_w<<<(F0 * F1 + 255) / 256, 256, 0, stream>>>(W1, W1t, F0, F1);
    transpose_w<<<(F1 * F1 + 255) / 256, 256, 0, stream>>>(W2, W2t, F1, F1);
    cast_scale_x<<<(N_NODES * (F0 / 2) + 255) / 256, 256, 0, stream>>>(x, dinv, xs);

    // conv1
    aggregate_bf<F0><<<(N_NODES + 3) / 4, 256, 0, stream>>>((const u16*)xs, offs, csr, dinv, aggx);
    gemm_mfma<F0, true><<<dim3((N_NODES + 127) / 128, 2), 256, 0, stream>>>(aggx, W1t, b1, dinv, hs1, N_NODES);

    // conv2
    aggregate_bf<F1><<<(N_NODES + 3) / 4, 256, 0, stream>>>(hs1, offs, csr, dinv, agg1);
    gemm_mfma<F1, false><<<dim3((N_NODES + 127) / 128, 2), 256, 0, stream>>>(agg1, W2t, b2, dinv, h2, N_NODES);

    // mean pool + classifier + log_softmax
    pool_kernel<<<N_GRAPHS, 256, 0, stream>>>(h2, goff, gpool);
    classify<<<N_GRAPHS, 64, 0, stream>>>(gpool, Wc, bc, out);
}

// Round 4
// 485.509 us; speedup vs baseline: 2.1806x; 1.1321x over previous
//
#include <hip/hip_runtime.h>
#include <hip/hip_bf16.h>

#define N_NODES 100000
#define N_EDGES 1600000
#define N_GRAPHS 2048
#define F0 128
#define F1 256
#define NCLS 64

// bucketed CSR build
#define BSHIFT 9
#define BNODES 512
#define NB 196
#define EPB 4096
#define NCHUNK 391
#define FLATN (NB * NCHUNK)

typedef unsigned int uint32;
typedef unsigned short u16;
typedef u16 u16x8 __attribute__((ext_vector_type(8)));
typedef __bf16 bf16x8 __attribute__((ext_vector_type(8)));
typedef float f32x4 __attribute__((ext_vector_type(4)));

__device__ __forceinline__ float blo(uint32 v) { return __builtin_bit_cast(float, v << 16); }
__device__ __forceinline__ float bhi(uint32 v) { return __builtin_bit_cast(float, v & 0xffff0000u); }
__device__ __forceinline__ float b16f(u16 v) { return __builtin_bit_cast(float, (uint32)v << 16); }
__device__ __forceinline__ u16 f2bf(float f) {
    uint32 u = __builtin_bit_cast(uint32, f);
    u += 0x7fffu + ((u >> 16) & 1u);  // RNE
    return (u16)(u >> 16);
}
__device__ __forceinline__ uint32 pack2(float a, float b) {
    return (uint32)f2bf(a) | ((uint32)f2bf(b) << 16);
}

// ---------------- generic scans (3-phase) ----------------
#define SCAN_B 1024

__global__ void scan_partial(const int* __restrict__ in, int n, int* __restrict__ bsum) {
    __shared__ int lds[SCAN_B];
    int i = blockIdx.x * SCAN_B + threadIdx.x;
    lds[threadIdx.x] = (i < n) ? in[i] : 0;
    __syncthreads();
    for (int s = SCAN_B / 2; s > 0; s >>= 1) {
        if (threadIdx.x < s) lds[threadIdx.x] += lds[threadIdx.x + s];
        __syncthreads();
    }
    if (threadIdx.x == 0) bsum[blockIdx.x] = lds[0];
}

__global__ void scan_bsum(int* __restrict__ bsum, int nb) {
    __shared__ int lds[SCAN_B];
    int v = (threadIdx.x < nb) ? bsum[threadIdx.x] : 0;
    lds[threadIdx.x] = v;
    __syncthreads();
    for (int s = 1; s < SCAN_B; s <<= 1) {
        int t = (threadIdx.x >= s) ? lds[threadIdx.x - s] : 0;
        __syncthreads();
        lds[threadIdx.x] += t;
        __syncthreads();
    }
    if (threadIdx.x < nb) bsum[threadIdx.x] = lds[threadIdx.x] - v;  // exclusive
}

__global__ void scan_final(const int* __restrict__ in, int n, const int* __restrict__ bsum,
                           int* __restrict__ out) {
    __shared__ int lds[SCAN_B];
    int i = blockIdx.x * SCAN_B + threadIdx.x;
    int v = (i < n) ? in[i] : 0;
    lds[threadIdx.x] = v;
    __syncthreads();
    for (int s = 1; s < SCAN_B; s <<= 1) {
        int t = (threadIdx.x >= s) ? lds[threadIdx.x - s] : 0;
        __syncthreads();
        lds[threadIdx.x] += t;
        __syncthreads();
    }
    if (i < n) out[i + 1] = lds[threadIdx.x] + bsum[blockIdx.x];
    if (i == 0) out[0] = 0;
}

// ---------------- bucketed CSR build ----------------

__global__ __launch_bounds__(256) void hist_pass(const int* __restrict__ dst,
                                                 int* __restrict__ hist) {
    __shared__ int lh[NB];
    int t = threadIdx.x, blk = blockIdx.x;
    if (t < NB) lh[t] = 0;
    __syncthreads();
#pragma unroll
    for (int k = 0; k < EPB / 256; ++k) {
        int e = blk * EPB + k * 256 + t;
        if (e < N_EDGES) atomicAdd(&lh[dst[e] >> BSHIFT], 1);
    }
    __syncthreads();
    if (t < NB) hist[t * NCHUNK + blk] = lh[t];
}

// pack: low 9 bits = dst&511, high bits = src (src < 2^17 -> fits 26 bits)
__global__ __launch_bounds__(256) void bin_pairs(const int* __restrict__ src,
                                                 const int* __restrict__ dst,
                                                 const int* __restrict__ histoff,
                                                 uint32* __restrict__ pairs) {
    __shared__ int lbase[NB];
    __shared__ int lcur[NB];
    int t = threadIdx.x, blk = blockIdx.x;
    if (t < NB) {
        lbase[t] = histoff[t * NCHUNK + blk];
        lcur[t] = 0;
    }
    __syncthreads();
#pragma unroll
    for (int k = 0; k < EPB / 256; ++k) {
        int e = blk * EPB + k * 256 + t;
        if (e < N_EDGES) {
            int d = dst[e], s = src[e];
            int b = d >> BSHIFT;
            int r = atomicAdd(&lcur[b], 1);
            pairs[lbase[b] + r] = (uint32)(d & (BNODES - 1)) | ((uint32)s << BSHIFT);
        }
    }
}

__global__ __launch_bounds__(256) void bucket_csr(const uint32* __restrict__ pairs,
                                                  const int* __restrict__ histoff,
                                                  int* __restrict__ offs,
                                                  int* __restrict__ csr,
                                                  float* __restrict__ dinv) {
    __shared__ int lcnt[BNODES];
    __shared__ int lcur[BNODES];
    __shared__ int psum[256];
    int t = threadIdx.x, b = blockIdx.x;
    int n0 = b << BSHIFT;
    int nn = min(BNODES, N_NODES - n0);
    lcnt[t] = 0;
    lcnt[t + 256] = 0;
    __syncthreads();
    int ebase = histoff[b * NCHUNK];
    int eend = (b == NB - 1) ? N_EDGES : histoff[(b + 1) * NCHUNK];
    for (int i = ebase + t; i < eend; i += 256) {
        atomicAdd(&lcnt[pairs[i] & (BNODES - 1)], 1);
    }
    __syncthreads();
    int c0 = lcnt[2 * t], c1 = lcnt[2 * t + 1];
    if (2 * t < nn) dinv[n0 + 2 * t] = rsqrtf((float)(c0 + 1));
    if (2 * t + 1 < nn) dinv[n0 + 2 * t + 1] = rsqrtf((float)(c1 + 1));
    psum[t] = c0 + c1;
    __syncthreads();
    for (int s = 1; s < 256; s <<= 1) {
        int v = (t >= s) ? psum[t - s] : 0;
        __syncthreads();
        psum[t] += v;
        __syncthreads();
    }
    int ep = psum[t] - (c0 + c1);
    lcur[2 * t] = ep;
    lcur[2 * t + 1] = ep + c0;
    if (2 * t < nn) offs[n0 + 2 * t] = ebase + ep;
    if (2 * t + 1 < nn) offs[n0 + 2 * t + 1] = ebase + ep + c0;
    if (b == NB - 1 && t == 0) offs[N_NODES] = N_EDGES;
    __syncthreads();
    for (int i = ebase + t; i < eend; i += 256) {
        uint32 p = pairs[i];
        int r = atomicAdd(&lcur[p & (BNODES - 1)], 1);
        csr[ebase + r] = (int)(p >> BSHIFT);
    }
}

// ---------------- batch histogram ----------------

__global__ void count_batch(const int* __restrict__ batch, int* __restrict__ gcnt) {
    int i = blockIdx.x * blockDim.x + threadIdx.x;
    if (i < N_NODES) {
        int b = batch[i];
        if ((unsigned)b < N_GRAPHS) atomicAdd(&gcnt[b], 1);
    }
}

// ---------------- casts ----------------

__global__ void cast_scale_x(const float* __restrict__ x, const float* __restrict__ dinv,
                             uint32* __restrict__ xs) {
    int idx = blockIdx.x * blockDim.x + threadIdx.x;
    if (idx >= N_NODES * (F0 / 2)) return;
    int node = idx / (F0 / 2);
    float d = dinv[node];
    float2 v = *(const float2*)&x[(size_t)idx * 2];
    xs[idx] = pack2(v.x * d, v.y * d);
}

__global__ void transpose_w(const float* __restrict__ W, u16* __restrict__ Wt, int K, int N) {
    int id = blockIdx.x * blockDim.x + threadIdx.x;
    if (id >= K * N) return;
    int k = id / N, n = id % N;
    Wt[(size_t)n * K + k] = f2bf(W[id]);
}

// ---------------- aggregation (gather, shfl-broadcast indices, 4-deep) ----------------

template <int F>
__global__ __launch_bounds__(256) void aggregate_bf(const u16* __restrict__ hs,
                                                    const int* __restrict__ offs,
                                                    const int* __restrict__ csr,
                                                    const float* __restrict__ dinv,
                                                    u16* __restrict__ out) {
    constexpr int V = F / 64;
    int node = blockIdx.x * 4 + (threadIdx.x >> 6);
    if (node >= N_NODES) return;
    int lane = threadIdx.x & 63;
    float acc[V];
    {
        const u16* selfp = hs + (size_t)node * F + lane * V;
        if constexpr (V == 2) {
            uint32 v = *(const uint32*)selfp;
            acc[0] = blo(v); acc[1] = bhi(v);
        } else {
            uint2 v = *(const uint2*)selfp;
            acc[0] = blo(v.x); acc[1] = bhi(v.x); acc[2] = blo(v.y); acc[3] = bhi(v.y);
        }
    }
    int e0 = offs[node], e1 = offs[node + 1];
    for (int b = e0; b < e1; b += 64) {
        int idx = (b + lane < e1) ? csr[b + lane] : 0;  // coalesced block-load of indices
        int cnt = min(64, e1 - b);
        int t = 0;
        for (; t + 4 <= cnt; t += 4) {
            int j0 = __shfl(idx, t), j1 = __shfl(idx, t + 1);
            int j2 = __shfl(idx, t + 2), j3 = __shfl(idx, t + 3);
            if constexpr (V == 2) {
                uint32 a = *(const uint32*)(hs + (size_t)j0 * F + lane * 2);
                uint32 c = *(const uint32*)(hs + (size_t)j1 * F + lane * 2);
                uint32 d = *(const uint32*)(hs + (size_t)j2 * F + lane * 2);
                uint32 f = *(const uint32*)(hs + (size_t)j3 * F + lane * 2);
                acc[0] += (blo(a) + blo(c)) + (blo(d) + blo(f));
                acc[1] += (bhi(a) + bhi(c)) + (bhi(d) + bhi(f));
            } else {
                uint2 a = *(const uint2*)(hs + (size_t)j0 * F + lane * 4);
                uint2 c = *(const uint2*)(hs + (size_t)j1 * F + lane * 4);
                uint2 d = *(const uint2*)(hs + (size_t)j2 * F + lane * 4);
                uint2 f = *(const uint2*)(hs + (size_t)j3 * F + lane * 4);
                acc[0] += (blo(a.x) + blo(c.x)) + (blo(d.x) + blo(f.x));
                acc[1] += (bhi(a.x) + bhi(c.x)) + (bhi(d.x) + bhi(f.x));
                acc[2] += (blo(a.y) + blo(c.y)) + (blo(d.y) + blo(f.y));
                acc[3] += (bhi(a.y) + bhi(c.y)) + (bhi(d.y) + bhi(f.y));
            }
        }
        for (; t < cnt; ++t) {
            int j0 = __shfl(idx, t);
            if constexpr (V == 2) {
                uint32 a = *(const uint32*)(hs + (size_t)j0 * F + lane * 2);
                acc[0] += blo(a); acc[1] += bhi(a);
            } else {
                uint2 a = *(const uint2*)(hs + (size_t)j0 * F + lane * 4);
                acc[0] += blo(a.x); acc[1] += bhi(a.x);
                acc[2] += blo(a.y); acc[3] += bhi(a.y);
            }
        }
    }
    float di = dinv[node];
    u16* orow = out + (size_t)node * F + lane * V;
    if constexpr (V == 2) {
        *(uint32*)orow = pack2(acc[0] * di, acc[1] * di);
    } else {
        uint2 o;
        o.x = pack2(acc[0] * di, acc[1] * di);
        o.y = pack2(acc[2] * di, acc[3] * di);
        *(uint2*)orow = o;
    }
}

// ---------------- bf16 MFMA GEMM + bias + relu; epilogue: row-scale OR fused mean-pool ----------------
// POOL=false: C[row][col] = bf16( relu(...) * (SCALE ? dinv[row] : 1) )
// POOL=true:  no C write; per-(graph,col) partial sums atomicAdd'ed into gpool (fp32)

template <int K, bool SCALE, bool POOL>
__global__ __launch_bounds__(256) void gemm_mfma(const u16* __restrict__ A,
                                                 const u16* __restrict__ Bt,
                                                 const float* __restrict__ bias,
                                                 const float* __restrict__ dinv,
                                                 u16* __restrict__ C, int M,
                                                 const int* __restrict__ batch,
                                                 float* __restrict__ gpool) {
    constexpr int BM = 128, BN = 128, BK = 64, BKP = 72;
    constexpr int NN = 256;
    __shared__ __align__(16) char smem[2 * BM * BKP * 2];  // 36864 B
    u16(*As)[BKP] = (u16(*)[BKP])smem;
    u16(*Bs)[BKP] = (u16(*)[BKP])(smem + BM * BKP * 2);
    int tid = threadIdx.x;
    int row0 = blockIdx.x * BM, col0 = blockIdx.y * BN;
    int lane = tid & 63, wid = tid >> 6;
    int wm = (wid >> 1) * 64, wn = (wid & 1) * 64;
    int lr = lane & 15, lq = lane >> 4;

    f32x4 acc[4][4];
#pragma unroll
    for (int i = 0; i < 4; ++i)
#pragma unroll
        for (int j = 0; j < 4; ++j) acc[i][j] = (f32x4){0.f, 0.f, 0.f, 0.f};

    for (int k0 = 0; k0 < K; k0 += BK) {
#pragma unroll
        for (int p = 0; p < 4; ++p) {
            int r = (tid >> 3) + p * 32;
            int c = (tid & 7) * 8;
            u16x8 av = {0, 0, 0, 0, 0, 0, 0, 0};
            int gr = row0 + r;
            if (gr < M) av = *(const u16x8*)&A[(size_t)gr * K + k0 + c];
            *(u16x8*)&As[r][c] = av;
            *(u16x8*)&Bs[r][c] = *(const u16x8*)&Bt[(size_t)(col0 + r) * K + k0 + c];
        }
        __syncthreads();
#pragma unroll
        for (int kk = 0; kk < BK; kk += 32) {
            bf16x8 af[4], bfr[4];
#pragma unroll
            for (int i = 0; i < 4; ++i)
                af[i] = __builtin_bit_cast(bf16x8, *(const u16x8*)&As[wm + i * 16 + lr][kk + lq * 8]);
#pragma unroll
            for (int j = 0; j < 4; ++j)
                bfr[j] = __builtin_bit_cast(bf16x8, *(const u16x8*)&Bs[wn + j * 16 + lr][kk + lq * 8]);
#pragma unroll
            for (int i = 0; i < 4; ++i)
#pragma unroll
                for (int j = 0; j < 4; ++j)
                    acc[i][j] = __builtin_amdgcn_mfma_f32_16x16x32_bf16(af[i], bfr[j], acc[i][j], 0, 0, 0);
        }
        __syncthreads();
    }

    if constexpr (!POOL) {
#pragma unroll
        for (int i = 0; i < 4; ++i) {
#pragma unroll
            for (int j = 0; j < 4; ++j) {
                int col = col0 + wn + j * 16 + lr;
                float bv = bias[col];
#pragma unroll
                for (int r = 0; r < 4; ++r) {
                    int row = row0 + wm + i * 16 + lq * 4 + r;
                    if (row < M) {
                        float v = fmaxf(acc[i][j][r] + bv, 0.f);
                        if constexpr (SCALE) v *= dinv[row];
                        C[(size_t)row * NN + col] = f2bf(v);
                    }
                }
            }
        }
    } else {
        // overlay: P[128][130] bf16 (33280 B) + batchl[128] int (512 B) fits in smem
        u16(*P)[130] = (u16(*)[130])smem;
        int* batchl = (int*)(smem + 33280);
        // stage relu'd tile to LDS (bf16, same rounding as the old h2 path)
#pragma unroll
        for (int i = 0; i < 4; ++i) {
#pragma unroll
            for (int j = 0; j < 4; ++j) {
                int cl = wn + j * 16 + lr;
                float bv = bias[col0 + cl];
#pragma unroll
                for (int r = 0; r < 4; ++r) {
                    int rl = wm + i * 16 + lq * 4 + r;
                    float v = (row0 + rl < M) ? fmaxf(acc[i][j][r] + bv, 0.f) : 0.f;
                    P[rl][cl] = f2bf(v);
                }
            }
        }
        if (tid < BM) {
            int row = row0 + tid;
            batchl[tid] = batch[row < M ? row : (M - 1)];
        }
        __syncthreads();
        // run-length reduce down sorted batch, one col per thread, 2 row-halves
        int c = tid & 127;
        int h = tid >> 7;
        int cur = batchl[h * 64];
        float sum = 0.f;
#pragma unroll 4
        for (int r = h * 64; r < h * 64 + 64; ++r) {
            int gb = batchl[r];
            float v = b16f(P[r][c]);
            if (gb != cur) {
                atomicAdd(&gpool[(size_t)cur * NN + col0 + c], sum);
                sum = 0.f;
                cur = gb;
            }
            sum += v;
        }
        atomicAdd(&gpool[(size_t)cur * NN + col0 + c], sum);
    }
}

// ---------------- classifier + log_softmax (divide pooled sums by count) ----------------

__global__ void classify(const float* __restrict__ gpool, const int* __restrict__ gcnt,
                         const float* __restrict__ Wc, const float* __restrict__ bc,
                         float* __restrict__ out) {
    int gr = blockIdx.x;
    int c = threadIdx.x;  // 0..63, single wave
    __shared__ float gl[F1];
    float inv = 1.f / fmaxf((float)gcnt[gr], 1.f);
    for (int k = c; k < F1; k += 64) gl[k] = gpool[(size_t)gr * F1 + k] * inv;
    __syncthreads();
    float acc = bc[c];
    for (int k = 0; k < F1; ++k) acc += gl[k] * Wc[k * NCLS + c];
    float m = acc;
    for (int s = 32; s > 0; s >>= 1) m = fmaxf(m, __shfl_xor(m, s, 64));
    float ex = __expf(acc - m);
    float sum = ex;
    for (int s = 32; s > 0; s >>= 1) sum += __shfl_xor(sum, s, 64);
    out[(size_t)gr * NCLS + c] = acc - m - __logf(sum);
}

// ---------------- launch ----------------

extern "C" void kernel_launch(void* const* d_in, const int* in_sizes, int n_in,
                              void* d_out, int out_size, void* d_ws, size_t ws_size,
                              hipStream_t stream) {
    const float* x = (const float*)d_in[0];
    const int* ei = (const int*)d_in[1];
    const int* batch = (const int*)d_in[2];
    const float* W1 = (const float*)d_in[3];
    const float* b1 = (const float*)d_in[4];
    const float* W2 = (const float*)d_in[5];
    const float* b2 = (const float*)d_in[6];
    const float* Wc = (const float*)d_in[7];
    const float* bc = (const float*)d_in[8];
    float* out = (float*)d_out;
    const int* src = ei;
    const int* dst = ei + N_EDGES;

    char* w = (char*)d_ws;
    auto take = [&](size_t n) { char* p = w; w += (n + 255) & ~(size_t)255; return p; };
    float* dinv = (float*)take((size_t)N_NODES * 4);
    int* offs = (int*)take((size_t)(N_NODES + 1) * 4);
    int* hist = (int*)take((size_t)FLATN * 4);
    int* histoff = (int*)take((size_t)(FLATN + 1) * 4);
    int* bsum = (int*)take((size_t)1024 * 4);
    int* gcnt = (int*)take((size_t)N_GRAPHS * 4);
    uint32* pairs = (uint32*)take((size_t)N_EDGES * 4);
    int* csr = (int*)take((size_t)N_EDGES * 4);
    uint32* xs = (uint32*)take((size_t)N_NODES * F0 * 2);
    u16* aggx = (u16*)take((size_t)N_NODES * F0 * 2);
    u16* hs1 = (u16*)take((size_t)N_NODES * F1 * 2);
    u16* agg1 = (u16*)take((size_t)N_NODES * F1 * 2);
    u16* W1t = (u16*)take((size_t)F0 * F1 * 2);
    u16* W2t = (u16*)take((size_t)F1 * F1 * 2);
    float* gpool = (float*)take((size_t)N_GRAPHS * F1 * 4);

    hipMemsetAsync(gcnt, 0, (size_t)N_GRAPHS * 4, stream);
    hipMemsetAsync(gpool, 0, (size_t)N_GRAPHS * F1 * 4, stream);

    // CSR build: hist -> scan -> bin -> per-bucket finalize (deg/dinv/offs/csr)
    hist_pass<<<NCHUNK, 256, 0, stream>>>(dst, hist);
    {
        int nb = (FLATN + SCAN_B - 1) / SCAN_B;  // 75
        scan_partial<<<nb, SCAN_B, 0, stream>>>(hist, FLATN, bsum);
        scan_bsum<<<1, SCAN_B, 0, stream>>>(bsum, nb);
        scan_final<<<nb, SCAN_B, 0, stream>>>(hist, FLATN, bsum, histoff);
    }
    bin_pairs<<<NCHUNK, 256, 0, stream>>>(src, dst, histoff, pairs);
    bucket_csr<<<NB, 256, 0, stream>>>(pairs, histoff, offs, csr, dinv);

    count_batch<<<(N_NODES + 255) / 256, 256, 0, stream>>>(batch, gcnt);

    // weight prep + x cast (scaled by dinv)
    transpose_w<<<(F0 * F1 + 255) / 256, 256, 0, stream>>>(W1, W1t, F0, F1);
    transpose_w<<<(F1 * F1 + 255) / 256, 256, 0, stream>>>(W2, W2t, F1, F1);
    cast_scale_x<<<(N_NODES * (F0 / 2) + 255) / 256, 256, 0, stream>>>(x, dinv, xs);

    // conv1
    aggregate_bf<F0><<<(N_NODES + 3) / 4, 256, 0, stream>>>((const u16*)xs, offs, csr, dinv, aggx);
    gemm_mfma<F0, true, false><<<dim3((N_NODES + 127) / 128, 2), 256, 0, stream>>>(
        aggx, W1t, b1, dinv, hs1, N_NODES, nullptr, nullptr);

    // conv2 (+ fused mean-pool)
    aggregate_bf<F1><<<(N_NODES + 3) / 4, 256, 0, stream>>>(hs1, offs, csr, dinv, agg1);
    gemm_mfma<F1, false, true><<<dim3((N_NODES + 127) / 128, 2), 256, 0, stream>>>(
        agg1, W2t, b2, dinv, nullptr, N_NODES, batch, gpool);

    // classifier + log_softmax
    classify<<<N_GRAPHS, 64, 0, stream>>>(gpool, gcnt, Wc, bc, out);
}

// Round 5
// 464.936 us; speedup vs baseline: 2.2771x; 1.0442x over previous
//
#include <hip/hip_runtime.h>
#include <hip/hip_bf16.h>

#define N_NODES 100000
#define N_EDGES 1600000
#define N_GRAPHS 2048
#define F0 128
#define F1 256
#define NCLS 64

// bucketed CSR build
#define BSHIFT 9
#define BNODES 512
#define NB 196
#define EPB 4096
#define NCHUNK 391
#define FLATN (NB * NCHUNK)

typedef unsigned int uint32;
typedef unsigned short u16;
typedef u16 u16x8 __attribute__((ext_vector_type(8)));
typedef __bf16 bf16x8 __attribute__((ext_vector_type(8)));
typedef float f32x4 __attribute__((ext_vector_type(4)));

__device__ __forceinline__ float blo(uint32 v) { return __builtin_bit_cast(float, v << 16); }
__device__ __forceinline__ float bhi(uint32 v) { return __builtin_bit_cast(float, v & 0xffff0000u); }
__device__ __forceinline__ float b16f(u16 v) { return __builtin_bit_cast(float, (uint32)v << 16); }
__device__ __forceinline__ u16 f2bf(float f) {
    uint32 u = __builtin_bit_cast(uint32, f);
    u += 0x7fffu + ((u >> 16) & 1u);  // RNE
    return (u16)(u >> 16);
}
__device__ __forceinline__ uint32 pack2(float a, float b) {
    return (uint32)f2bf(a) | ((uint32)f2bf(b) << 16);
}

// ---------------- generic scans (3-phase) ----------------
#define SCAN_B 1024

__global__ void scan_partial(const int* __restrict__ in, int n, int* __restrict__ bsum) {
    __shared__ int lds[SCAN_B];
    int i = blockIdx.x * SCAN_B + threadIdx.x;
    lds[threadIdx.x] = (i < n) ? in[i] : 0;
    __syncthreads();
    for (int s = SCAN_B / 2; s > 0; s >>= 1) {
        if (threadIdx.x < s) lds[threadIdx.x] += lds[threadIdx.x + s];
        __syncthreads();
    }
    if (threadIdx.x == 0) bsum[blockIdx.x] = lds[0];
}

__global__ void scan_bsum(int* __restrict__ bsum, int nb) {
    __shared__ int lds[SCAN_B];
    int v = (threadIdx.x < nb) ? bsum[threadIdx.x] : 0;
    lds[threadIdx.x] = v;
    __syncthreads();
    for (int s = 1; s < SCAN_B; s <<= 1) {
        int t = (threadIdx.x >= s) ? lds[threadIdx.x - s] : 0;
        __syncthreads();
        lds[threadIdx.x] += t;
        __syncthreads();
    }
    if (threadIdx.x < nb) bsum[threadIdx.x] = lds[threadIdx.x] - v;  // exclusive
}

__global__ void scan_final(const int* __restrict__ in, int n, const int* __restrict__ bsum,
                           int* __restrict__ out) {
    __shared__ int lds[SCAN_B];
    int i = blockIdx.x * SCAN_B + threadIdx.x;
    int v = (i < n) ? in[i] : 0;
    lds[threadIdx.x] = v;
    __syncthreads();
    for (int s = 1; s < SCAN_B; s <<= 1) {
        int t = (threadIdx.x >= s) ? lds[threadIdx.x - s] : 0;
        __syncthreads();
        lds[threadIdx.x] += t;
        __syncthreads();
    }
    if (i < n) out[i + 1] = lds[threadIdx.x] + bsum[blockIdx.x];
    if (i == 0) out[0] = 0;
}

// ---------------- bucketed CSR build ----------------

__global__ __launch_bounds__(256) void hist_pass(const int* __restrict__ dst,
                                                 int* __restrict__ hist) {
    __shared__ int lh[NB];
    int t = threadIdx.x, blk = blockIdx.x;
    if (t < NB) lh[t] = 0;
    __syncthreads();
#pragma unroll
    for (int k = 0; k < EPB / 256; ++k) {
        int e = blk * EPB + k * 256 + t;
        if (e < N_EDGES) atomicAdd(&lh[dst[e] >> BSHIFT], 1);
    }
    __syncthreads();
    if (t < NB) hist[t * NCHUNK + blk] = lh[t];
}

// pack: low 9 bits = dst&511, high bits = src
__global__ __launch_bounds__(256) void bin_pairs(const int* __restrict__ src,
                                                 const int* __restrict__ dst,
                                                 const int* __restrict__ histoff,
                                                 uint32* __restrict__ pairs) {
    __shared__ int lbase[NB];
    __shared__ int lcur[NB];
    int t = threadIdx.x, blk = blockIdx.x;
    if (t < NB) {
        lbase[t] = histoff[t * NCHUNK + blk];
        lcur[t] = 0;
    }
    __syncthreads();
#pragma unroll
    for (int k = 0; k < EPB / 256; ++k) {
        int e = blk * EPB + k * 256 + t;
        if (e < N_EDGES) {
            int d = dst[e], s = src[e];
            int b = d >> BSHIFT;
            int r = atomicAdd(&lcur[b], 1);
            pairs[lbase[b] + r] = (uint32)(d & (BNODES - 1)) | ((uint32)s << BSHIFT);
        }
    }
}

__global__ __launch_bounds__(256) void bucket_csr(const uint32* __restrict__ pairs,
                                                  const int* __restrict__ histoff,
                                                  int* __restrict__ offs,
                                                  int* __restrict__ csr,
                                                  float* __restrict__ dinv) {
    __shared__ int lcnt[BNODES];
    __shared__ int lcur[BNODES];
    __shared__ int psum[256];
    int t = threadIdx.x, b = blockIdx.x;
    int n0 = b << BSHIFT;
    int nn = min(BNODES, N_NODES - n0);
    lcnt[t] = 0;
    lcnt[t + 256] = 0;
    __syncthreads();
    int ebase = histoff[b * NCHUNK];
    int eend = (b == NB - 1) ? N_EDGES : histoff[(b + 1) * NCHUNK];
    for (int i = ebase + t; i < eend; i += 256) {
        atomicAdd(&lcnt[pairs[i] & (BNODES - 1)], 1);
    }
    __syncthreads();
    int c0 = lcnt[2 * t], c1 = lcnt[2 * t + 1];
    if (2 * t < nn) dinv[n0 + 2 * t] = rsqrtf((float)(c0 + 1));
    if (2 * t + 1 < nn) dinv[n0 + 2 * t + 1] = rsqrtf((float)(c1 + 1));
    psum[t] = c0 + c1;
    __syncthreads();
    for (int s = 1; s < 256; s <<= 1) {
        int v = (t >= s) ? psum[t - s] : 0;
        __syncthreads();
        psum[t] += v;
        __syncthreads();
    }
    int ep = psum[t] - (c0 + c1);
    lcur[2 * t] = ep;
    lcur[2 * t + 1] = ep + c0;
    if (2 * t < nn) offs[n0 + 2 * t] = ebase + ep;
    if (2 * t + 1 < nn) offs[n0 + 2 * t + 1] = ebase + ep + c0;
    if (b == NB - 1 && t == 0) offs[N_NODES] = N_EDGES;
    __syncthreads();
    for (int i = ebase + t; i < eend; i += 256) {
        uint32 p = pairs[i];
        int r = atomicAdd(&lcur[p & (BNODES - 1)], 1);
        csr[ebase + r] = (int)(p >> BSHIFT);
    }
}

// ---------------- quantize x (wave per node): int8 row + fp32 scale; fuses count_batch ----------------

__global__ __launch_bounds__(256) void cast_q8_x(const float* __restrict__ x,
                                                 const float* __restrict__ dinv,
                                                 const int* __restrict__ batch,
                                                 u16* __restrict__ q8,
                                                 float* __restrict__ qs,
                                                 int* __restrict__ gcnt) {
    int node = blockIdx.x * 4 + (threadIdx.x >> 6);
    if (node >= N_NODES) return;
    int lane = threadIdx.x & 63;
    float d = dinv[node];
    float2 v = *(const float2*)&x[(size_t)node * F0 + lane * 2];
    float f0 = v.x * d, f1 = v.y * d;
    float m = fmaxf(fabsf(f0), fabsf(f1));
    for (int s = 32; s > 0; s >>= 1) m = fmaxf(m, __shfl_xor(m, s, 64));
    float inv = (m > 0.f) ? 127.f / m : 0.f;
    int q0 = (int)rintf(f0 * inv), q1 = (int)rintf(f1 * inv);
    q8[(size_t)node * 64 + lane] = (u16)((q0 & 255) | ((q1 & 255) << 8));
    if (lane == 0) {
        qs[node] = m * (1.f / 127.f);
        atomicAdd(&gcnt[batch[node]], 1);
    }
}

// ---------------- quantize hs1 rows (values >= 0 post-relu) ----------------

__global__ __launch_bounds__(256) void quantize_rows(const u16* __restrict__ hs1,
                                                     uint32* __restrict__ q8,
                                                     float* __restrict__ qs) {
    int node = blockIdx.x * 4 + (threadIdx.x >> 6);
    if (node >= N_NODES) return;
    int lane = threadIdx.x & 63;
    uint2 v = *(const uint2*)&hs1[(size_t)node * F1 + lane * 4];
    float f0 = blo(v.x), f1 = bhi(v.x), f2 = blo(v.y), f3 = bhi(v.y);
    float m = fmaxf(fmaxf(f0, f1), fmaxf(f2, f3));  // all >= 0
    for (int s = 32; s > 0; s >>= 1) m = fmaxf(m, __shfl_xor(m, s, 64));
    float inv = (m > 0.f) ? 127.f / m : 0.f;
    int q0 = (int)rintf(f0 * inv), q1 = (int)rintf(f1 * inv);
    int q2 = (int)rintf(f2 * inv), q3 = (int)rintf(f3 * inv);
    q8[(size_t)node * 64 + lane] =
        (uint32)(q0 & 255) | ((uint32)(q1 & 255) << 8) | ((uint32)(q2 & 255) << 16) | ((uint32)q3 << 24);
    if (lane == 0) qs[node] = m * (1.f / 127.f);
}

// ---------------- weight transpose+cast (both layers, one launch) ----------------

__global__ void transpose_w2(const float* __restrict__ W1, const float* __restrict__ W2,
                             u16* __restrict__ W1t, u16* __restrict__ W2t) {
    int id = blockIdx.x * blockDim.x + threadIdx.x;
    if (id < F0 * F1) {
        int k = id / F1, n = id % F1;
        W1t[(size_t)n * F0 + k] = f2bf(W1[id]);
    } else {
        int id2 = id - F0 * F1;
        if (id2 < F1 * F1) {
            int k = id2 / F1, n = id2 % F1;
            W2t[(size_t)n * F1 + k] = f2bf(W2[id2]);
        }
    }
}

// ---------------- int8 gather aggregation ----------------
// rows q8[j]*qs[j] are h[j]*dinv[j]; out[i] = bf16( dinv[i] * (sum_j deq(j) + deq(i)) )
// row layout: 64 lanes x (V int8), V=2 -> u16/lane, V=4 -> dword/lane

template <int F>
__global__ __launch_bounds__(256) void aggregate_q8(const void* __restrict__ q8,
                                                    const float* __restrict__ qs,
                                                    const int* __restrict__ offs,
                                                    const int* __restrict__ csr,
                                                    const float* __restrict__ dinv,
                                                    u16* __restrict__ out) {
    constexpr int V = F / 64;
    int node = blockIdx.x * 4 + (threadIdx.x >> 6);
    if (node >= N_NODES) return;
    int lane = threadIdx.x & 63;
    float acc[V];
    {
        float s = qs[node];
        if constexpr (V == 2) {
            int q = (int)((const u16*)q8)[(size_t)node * 64 + lane];
            acc[0] = (float)((q << 24) >> 24) * s;
            acc[1] = (float)((q << 16) >> 24) * s;
        } else {
            int q = (int)((const uint32*)q8)[(size_t)node * 64 + lane];
            acc[0] = (float)((q << 24) >> 24) * s;
            acc[1] = (float)((q << 16) >> 24) * s;
            acc[2] = (float)((q << 8) >> 24) * s;
            acc[3] = (float)(q >> 24) * s;
        }
    }
    int e0 = offs[node], e1 = offs[node + 1];
    for (int b = e0; b < e1; b += 64) {
        bool valid = (b + lane) < e1;
        int idx = valid ? csr[b + lane] : 0;
        float sv = valid ? qs[idx] : 0.f;
        int cnt = min(64, e1 - b);
        int t = 0;
        for (; t + 4 <= cnt; t += 4) {
            int j0 = __shfl(idx, t), j1 = __shfl(idx, t + 1);
            int j2 = __shfl(idx, t + 2), j3 = __shfl(idx, t + 3);
            float s0 = __shfl(sv, t), s1 = __shfl(sv, t + 1);
            float s2 = __shfl(sv, t + 2), s3 = __shfl(sv, t + 3);
            if constexpr (V == 2) {
                int a = (int)((const u16*)q8)[(size_t)j0 * 64 + lane];
                int c = (int)((const u16*)q8)[(size_t)j1 * 64 + lane];
                int d = (int)((const u16*)q8)[(size_t)j2 * 64 + lane];
                int f = (int)((const u16*)q8)[(size_t)j3 * 64 + lane];
                acc[0] += (float)((a << 24) >> 24) * s0 + (float)((c << 24) >> 24) * s1 +
                          (float)((d << 24) >> 24) * s2 + (float)((f << 24) >> 24) * s3;
                acc[1] += (float)((a << 16) >> 24) * s0 + (float)((c << 16) >> 24) * s1 +
                          (float)((d << 16) >> 24) * s2 + (float)((f << 16) >> 24) * s3;
            } else {
                int a = (int)((const uint32*)q8)[(size_t)j0 * 64 + lane];
                int c = (int)((const uint32*)q8)[(size_t)j1 * 64 + lane];
                int d = (int)((const uint32*)q8)[(size_t)j2 * 64 + lane];
                int f = (int)((const uint32*)q8)[(size_t)j3 * 64 + lane];
                acc[0] += (float)((a << 24) >> 24) * s0 + (float)((c << 24) >> 24) * s1 +
                          (float)((d << 24) >> 24) * s2 + (float)((f << 24) >> 24) * s3;
                acc[1] += (float)((a << 16) >> 24) * s0 + (float)((c << 16) >> 24) * s1 +
                          (float)((d << 16) >> 24) * s2 + (float)((f << 16) >> 24) * s3;
                acc[2] += (float)((a << 8) >> 24) * s0 + (float)((c << 8) >> 24) * s1 +
                          (float)((d << 8) >> 24) * s2 + (float)((f << 8) >> 24) * s3;
                acc[3] += (float)(a >> 24) * s0 + (float)(c >> 24) * s1 +
                          (float)(d >> 24) * s2 + (float)(f >> 24) * s3;
            }
        }
        for (; t < cnt; ++t) {
            int j0 = __shfl(idx, t);
            float s0 = __shfl(sv, t);
            if constexpr (V == 2) {
                int a = (int)((const u16*)q8)[(size_t)j0 * 64 + lane];
                acc[0] += (float)((a << 24) >> 24) * s0;
                acc[1] += (float)((a << 16) >> 24) * s0;
            } else {
                int a = (int)((const uint32*)q8)[(size_t)j0 * 64 + lane];
                acc[0] += (float)((a << 24) >> 24) * s0;
                acc[1] += (float)((a << 16) >> 24) * s0;
                acc[2] += (float)((a << 8) >> 24) * s0;
                acc[3] += (float)(a >> 24) * s0;
            }
        }
    }
    float di = dinv[node];
    u16* orow = out + (size_t)node * F + lane * V;
    if constexpr (V == 2) {
        *(uint32*)orow = pack2(acc[0] * di, acc[1] * di);
    } else {
        uint2 o;
        o.x = pack2(acc[0] * di, acc[1] * di);
        o.y = pack2(acc[2] * di, acc[3] * di);
        *(uint2*)orow = o;
    }
}

// ---------------- bf16 MFMA GEMM + bias + relu; epilogue: row-scale OR fused mean-pool ----------------

template <int K, bool SCALE, bool POOL>
__global__ __launch_bounds__(256) void gemm_mfma(const u16* __restrict__ A,
                                                 const u16* __restrict__ Bt,
                                                 const float* __restrict__ bias,
                                                 const float* __restrict__ dinv,
                                                 u16* __restrict__ C, int M,
                                                 const int* __restrict__ batch,
                                                 float* __restrict__ gpool) {
    constexpr int BM = 128, BN = 128, BK = 64, BKP = 72;
    constexpr int NN = 256;
    __shared__ __align__(16) char smem[2 * BM * BKP * 2];  // 36864 B
    u16(*As)[BKP] = (u16(*)[BKP])smem;
    u16(*Bs)[BKP] = (u16(*)[BKP])(smem + BM * BKP * 2);
    int tid = threadIdx.x;
    int row0 = blockIdx.x * BM, col0 = blockIdx.y * BN;
    int lane = tid & 63, wid = tid >> 6;
    int wm = (wid >> 1) * 64, wn = (wid & 1) * 64;
    int lr = lane & 15, lq = lane >> 4;

    f32x4 acc[4][4];
#pragma unroll
    for (int i = 0; i < 4; ++i)
#pragma unroll
        for (int j = 0; j < 4; ++j) acc[i][j] = (f32x4){0.f, 0.f, 0.f, 0.f};

    for (int k0 = 0; k0 < K; k0 += BK) {
#pragma unroll
        for (int p = 0; p < 4; ++p) {
            int r = (tid >> 3) + p * 32;
            int c = (tid & 7) * 8;
            u16x8 av = {0, 0, 0, 0, 0, 0, 0, 0};
            int gr = row0 + r;
            if (gr < M) av = *(const u16x8*)&A[(size_t)gr * K + k0 + c];
            *(u16x8*)&As[r][c] = av;
            *(u16x8*)&Bs[r][c] = *(const u16x8*)&Bt[(size_t)(col0 + r) * K + k0 + c];
        }
        __syncthreads();
#pragma unroll
        for (int kk = 0; kk < BK; kk += 32) {
            bf16x8 af[4], bfr[4];
#pragma unroll
            for (int i = 0; i < 4; ++i)
                af[i] = __builtin_bit_cast(bf16x8, *(const u16x8*)&As[wm + i * 16 + lr][kk + lq * 8]);
#pragma unroll
            for (int j = 0; j < 4; ++j)
                bfr[j] = __builtin_bit_cast(bf16x8, *(const u16x8*)&Bs[wn + j * 16 + lr][kk + lq * 8]);
#pragma unroll
            for (int i = 0; i < 4; ++i)
#pragma unroll
                for (int j = 0; j < 4; ++j)
                    acc[i][j] = __builtin_amdgcn_mfma_f32_16x16x32_bf16(af[i], bfr[j], acc[i][j], 0, 0, 0);
        }
        __syncthreads();
    }

    if constexpr (!POOL) {
#pragma unroll
        for (int i = 0; i < 4; ++i) {
#pragma unroll
            for (int j = 0; j < 4; ++j) {
                int col = col0 + wn + j * 16 + lr;
                float bv = bias[col];
#pragma unroll
                for (int r = 0; r < 4; ++r) {
                    int row = row0 + wm + i * 16 + lq * 4 + r;
                    if (row < M) {
                        float v = fmaxf(acc[i][j][r] + bv, 0.f);
                        if constexpr (SCALE) v *= dinv[row];
                        C[(size_t)row * NN + col] = f2bf(v);
                    }
                }
            }
        }
    } else {
        u16(*P)[130] = (u16(*)[130])smem;
        int* batchl = (int*)(smem + 33280);
#pragma unroll
        for (int i = 0; i < 4; ++i) {
#pragma unroll
            for (int j = 0; j < 4; ++j) {
                int cl = wn + j * 16 + lr;
                float bv = bias[col0 + cl];
#pragma unroll
                for (int r = 0; r < 4; ++r) {
                    int rl = wm + i * 16 + lq * 4 + r;
                    float v = (row0 + rl < M) ? fmaxf(acc[i][j][r] + bv, 0.f) : 0.f;
                    P[rl][cl] = f2bf(v);
                }
            }
        }
        if (tid < BM) {
            int row = row0 + tid;
            batchl[tid] = batch[row < M ? row : (M - 1)];
        }
        __syncthreads();
        int c = tid & 127;
        int h = tid >> 7;
        int cur = batchl[h * 64];
        float sum = 0.f;
#pragma unroll 4
        for (int r = h * 64; r < h * 64 + 64; ++r) {
            int gb = batchl[r];
            float v = b16f(P[r][c]);
            if (gb != cur) {
                atomicAdd(&gpool[(size_t)cur * NN + col0 + c], sum);
                sum = 0.f;
                cur = gb;
            }
            sum += v;
        }
        atomicAdd(&gpool[(size_t)cur * NN + col0 + c], sum);
    }
}

// ---------------- classifier + log_softmax ----------------

__global__ void classify(const float* __restrict__ gpool, const int* __restrict__ gcnt,
                         const float* __restrict__ Wc, const float* __restrict__ bc,
                         float* __restrict__ out) {
    int gr = blockIdx.x;
    int c = threadIdx.x;  // 0..63, single wave
    __shared__ float gl[F1];
    float inv = 1.f / fmaxf((float)gcnt[gr], 1.f);
    for (int k = c; k < F1; k += 64) gl[k] = gpool[(size_t)gr * F1 + k] * inv;
    __syncthreads();
    float acc = bc[c];
    for (int k = 0; k < F1; ++k) acc += gl[k] * Wc[k * NCLS + c];
    float m = acc;
    for (int s = 32; s > 0; s >>= 1) m = fmaxf(m, __shfl_xor(m, s, 64));
    float ex = __expf(acc - m);
    float sum = ex;
    for (int s = 32; s > 0; s >>= 1) sum += __shfl_xor(sum, s, 64);
    out[(size_t)gr * NCLS + c] = acc - m - __logf(sum);
}

// ---------------- launch ----------------

extern "C" void kernel_launch(void* const* d_in, const int* in_sizes, int n_in,
                              void* d_out, int out_size, void* d_ws, size_t ws_size,
                              hipStream_t stream) {
    const float* x = (const float*)d_in[0];
    const int* ei = (const int*)d_in[1];
    const int* batch = (const int*)d_in[2];
    const float* W1 = (const float*)d_in[3];
    const float* b1 = (const float*)d_in[4];
    const float* W2 = (const float*)d_in[5];
    const float* b2 = (const float*)d_in[6];
    const float* Wc = (const float*)d_in[7];
    const float* bc = (const float*)d_in[8];
    float* out = (float*)d_out;
    const int* src = ei;
    const int* dst = ei + N_EDGES;

    char* w = (char*)d_ws;
    auto take = [&](size_t n) { char* p = w; w += (n + 255) & ~(size_t)255; return p; };
    float* dinv = (float*)take((size_t)N_NODES * 4);
    int* offs = (int*)take((size_t)(N_NODES + 1) * 4);
    int* hist = (int*)take((size_t)FLATN * 4);
    int* histoff = (int*)take((size_t)(FLATN + 1) * 4);
    int* bsum = (int*)take((size_t)1024 * 4);
    int* gcnt = (int*)take((size_t)N_GRAPHS * 4);
    uint32* pairs = (uint32*)take((size_t)N_EDGES * 4);
    int* csr = (int*)take((size_t)N_EDGES * 4);
    u16* q8x = (u16*)take((size_t)N_NODES * 64 * 2);        // int8 x*dinv rows (128 B/row)
    float* qsx = (float*)take((size_t)N_NODES * 4);
    uint32* q8h = (uint32*)take((size_t)N_NODES * 64 * 4);  // int8 hs1 rows (256 B/row)
    float* qsh = (float*)take((size_t)N_NODES * 4);
    u16* aggx = (u16*)take((size_t)N_NODES * F0 * 2);       // bf16
    u16* hs1 = (u16*)take((size_t)N_NODES * F1 * 2);        // bf16, dinv-scaled
    u16* agg1 = (u16*)take((size_t)N_NODES * F1 * 2);       // bf16
    u16* W1t = (u16*)take((size_t)F0 * F1 * 2);
    u16* W2t = (u16*)take((size_t)F1 * F1 * 2);
    float* gpool = (float*)take((size_t)N_GRAPHS * F1 * 4);

    hipMemsetAsync(gcnt, 0, (size_t)N_GRAPHS * 4, stream);
    hipMemsetAsync(gpool, 0, (size_t)N_GRAPHS * F1 * 4, stream);

    // CSR build: hist -> scan -> bin -> per-bucket finalize (deg/dinv/offs/csr)
    hist_pass<<<NCHUNK, 256, 0, stream>>>(dst, hist);
    {
        int nb = (FLATN + SCAN_B - 1) / SCAN_B;  // 75
        scan_partial<<<nb, SCAN_B, 0, stream>>>(hist, FLATN, bsum);
        scan_bsum<<<1, SCAN_B, 0, stream>>>(bsum, nb);
        scan_final<<<nb, SCAN_B, 0, stream>>>(hist, FLATN, bsum, histoff);
    }
    bin_pairs<<<NCHUNK, 256, 0, stream>>>(src, dst, histoff, pairs);
    bucket_csr<<<NB, 256, 0, stream>>>(pairs, histoff, offs, csr, dinv);

    // weight prep + x quantize (scaled by dinv; also counts batch)
    transpose_w2<<<(F0 * F1 + F1 * F1 + 255) / 256, 256, 0, stream>>>(W1, W2, W1t, W2t);
    cast_q8_x<<<(N_NODES + 3) / 4, 256, 0, stream>>>(x, dinv, batch, q8x, qsx, gcnt);

    // conv1: int8 gather-aggregate -> bf16, MFMA GEMM (+b1, relu, *dinv)
    aggregate_q8<F0><<<(N_NODES + 3) / 4, 256, 0, stream>>>(q8x, qsx, offs, csr, dinv, aggx);
    gemm_mfma<F0, true, false><<<dim3((N_NODES + 127) / 128, 2), 256, 0, stream>>>(
        aggx, W1t, b1, dinv, hs1, N_NODES, nullptr, nullptr);

    // quantize hs1 rows to int8
    quantize_rows<<<(N_NODES + 3) / 4, 256, 0, stream>>>(hs1, q8h, qsh);

    // conv2: int8 gather-aggregate -> bf16, MFMA GEMM (+b2, relu) + fused mean-pool
    aggregate_q8<F1><<<(N_NODES + 3) / 4, 256, 0, stream>>>(q8h, qsh, offs, csr, dinv, agg1);
    gemm_mfma<F1, false, true><<<dim3((N_NODES + 127) / 128, 2), 256, 0, stream>>>(
        agg1, W2t, b2, dinv, nullptr, N_NODES, batch, gpool);

    // classifier + log_softmax
    classify<<<N_GRAPHS, 64, 0, stream>>>(gpool, gcnt, Wc, bc, out);
}

// Round 6
// 460.448 us; speedup vs baseline: 2.2993x; 1.0097x over previous
//
#include <hip/hip_runtime.h>
#include <hip/hip_bf16.h>

#define N_NODES 100000
#define N_EDGES 1600000
#define N_GRAPHS 2048
#define F0 128
#define F1 256
#define NCLS 64

// bucketed CSR build
#define BSHIFT 9
#define BNODES 512
#define NB 196
#define EPB 4096
#define NCHUNK 391
#define FLATN (NB * NCHUNK)

typedef unsigned int uint32;
typedef unsigned short u16;
typedef u16 u16x8 __attribute__((ext_vector_type(8)));
typedef __bf16 bf16x8 __attribute__((ext_vector_type(8)));
typedef float f32x4 __attribute__((ext_vector_type(4)));

__device__ __forceinline__ float blo(uint32 v) { return __builtin_bit_cast(float, v << 16); }
__device__ __forceinline__ float bhi(uint32 v) { return __builtin_bit_cast(float, v & 0xffff0000u); }
__device__ __forceinline__ float b16f(u16 v) { return __builtin_bit_cast(float, (uint32)v << 16); }
__device__ __forceinline__ u16 f2bf(float f) {
    uint32 u = __builtin_bit_cast(uint32, f);
    u += 0x7fffu + ((u >> 16) & 1u);  // RNE
    return (u16)(u >> 16);
}
__device__ __forceinline__ uint32 pack2(float a, float b) {
    return (uint32)f2bf(a) | ((uint32)f2bf(b) << 16);
}
// biased-u8 dequant helpers: compiler emits v_cvt_f32_ubyte0..3
__device__ __forceinline__ float ub0(uint32 u) { return (float)(u & 255u); }
__device__ __forceinline__ float ub1(uint32 u) { return (float)((u >> 8) & 255u); }
__device__ __forceinline__ float ub2(uint32 u) { return (float)((u >> 16) & 255u); }
__device__ __forceinline__ float ub3(uint32 u) { return (float)(u >> 24); }

// ---------------- generic scans (3-phase) ----------------
#define SCAN_B 1024

__global__ void scan_partial(const int* __restrict__ in, int n, int* __restrict__ bsum) {
    __shared__ int lds[SCAN_B];
    int i = blockIdx.x * SCAN_B + threadIdx.x;
    lds[threadIdx.x] = (i < n) ? in[i] : 0;
    __syncthreads();
    for (int s = SCAN_B / 2; s > 0; s >>= 1) {
        if (threadIdx.x < s) lds[threadIdx.x] += lds[threadIdx.x + s];
        __syncthreads();
    }
    if (threadIdx.x == 0) bsum[blockIdx.x] = lds[0];
}

__global__ void scan_bsum(int* __restrict__ bsum, int nb) {
    __shared__ int lds[SCAN_B];
    int v = (threadIdx.x < nb) ? bsum[threadIdx.x] : 0;
    lds[threadIdx.x] = v;
    __syncthreads();
    for (int s = 1; s < SCAN_B; s <<= 1) {
        int t = (threadIdx.x >= s) ? lds[threadIdx.x - s] : 0;
        __syncthreads();
        lds[threadIdx.x] += t;
        __syncthreads();
    }
    if (threadIdx.x < nb) bsum[threadIdx.x] = lds[threadIdx.x] - v;  // exclusive
}

__global__ void scan_final(const int* __restrict__ in, int n, const int* __restrict__ bsum,
                           int* __restrict__ out) {
    __shared__ int lds[SCAN_B];
    int i = blockIdx.x * SCAN_B + threadIdx.x;
    int v = (i < n) ? in[i] : 0;
    lds[threadIdx.x] = v;
    __syncthreads();
    for (int s = 1; s < SCAN_B; s <<= 1) {
        int t = (threadIdx.x >= s) ? lds[threadIdx.x - s] : 0;
        __syncthreads();
        lds[threadIdx.x] += t;
        __syncthreads();
    }
    if (i < n) out[i + 1] = lds[threadIdx.x] + bsum[blockIdx.x];
    if (i == 0) out[0] = 0;
}

// ---------------- bucketed CSR build ----------------

__global__ __launch_bounds__(256) void hist_pass(const int* __restrict__ dst,
                                                 int* __restrict__ hist) {
    __shared__ int lh[NB];
    int t = threadIdx.x, blk = blockIdx.x;
    if (t < NB) lh[t] = 0;
    __syncthreads();
#pragma unroll
    for (int k = 0; k < EPB / 256; ++k) {
        int e = blk * EPB + k * 256 + t;
        if (e < N_EDGES) atomicAdd(&lh[dst[e] >> BSHIFT], 1);
    }
    __syncthreads();
    if (t < NB) hist[t * NCHUNK + blk] = lh[t];
}

__global__ __launch_bounds__(256) void bin_pairs(const int* __restrict__ src,
                                                 const int* __restrict__ dst,
                                                 const int* __restrict__ histoff,
                                                 uint32* __restrict__ pairs) {
    __shared__ int lbase[NB];
    __shared__ int lcur[NB];
    int t = threadIdx.x, blk = blockIdx.x;
    if (t < NB) {
        lbase[t] = histoff[t * NCHUNK + blk];
        lcur[t] = 0;
    }
    __syncthreads();
#pragma unroll
    for (int k = 0; k < EPB / 256; ++k) {
        int e = blk * EPB + k * 256 + t;
        if (e < N_EDGES) {
            int d = dst[e], s = src[e];
            int b = d >> BSHIFT;
            int r = atomicAdd(&lcur[b], 1);
            pairs[lbase[b] + r] = (uint32)(d & (BNODES - 1)) | ((uint32)s << BSHIFT);
        }
    }
}

__global__ __launch_bounds__(256) void bucket_csr(const uint32* __restrict__ pairs,
                                                  const int* __restrict__ histoff,
                                                  int* __restrict__ offs,
                                                  int* __restrict__ csr,
                                                  float* __restrict__ dinv) {
    __shared__ int lcnt[BNODES];
    __shared__ int lcur[BNODES];
    __shared__ int psum[256];
    int t = threadIdx.x, b = blockIdx.x;
    int n0 = b << BSHIFT;
    int nn = min(BNODES, N_NODES - n0);
    lcnt[t] = 0;
    lcnt[t + 256] = 0;
    __syncthreads();
    int ebase = histoff[b * NCHUNK];
    int eend = (b == NB - 1) ? N_EDGES : histoff[(b + 1) * NCHUNK];
    for (int i = ebase + t; i < eend; i += 256) {
        atomicAdd(&lcnt[pairs[i] & (BNODES - 1)], 1);
    }
    __syncthreads();
    int c0 = lcnt[2 * t], c1 = lcnt[2 * t + 1];
    if (2 * t < nn) dinv[n0 + 2 * t] = rsqrtf((float)(c0 + 1));
    if (2 * t + 1 < nn) dinv[n0 + 2 * t + 1] = rsqrtf((float)(c1 + 1));
    psum[t] = c0 + c1;
    __syncthreads();
    for (int s = 1; s < 256; s <<= 1) {
        int v = (t >= s) ? psum[t - s] : 0;
        __syncthreads();
        psum[t] += v;
        __syncthreads();
    }
    int ep = psum[t] - (c0 + c1);
    lcur[2 * t] = ep;
    lcur[2 * t + 1] = ep + c0;
    if (2 * t < nn) offs[n0 + 2 * t] = ebase + ep;
    if (2 * t + 1 < nn) offs[n0 + 2 * t + 1] = ebase + ep + c0;
    if (b == NB - 1 && t == 0) offs[N_NODES] = N_EDGES;
    __syncthreads();
    for (int i = ebase + t; i < eend; i += 256) {
        uint32 p = pairs[i];
        int r = atomicAdd(&lcur[p & (BNODES - 1)], 1);
        csr[ebase + r] = (int)(p >> BSHIFT);
    }
}

// ---------------- quantize x: biased u8 row + fp32 scale; fuses count_batch ----------------

__global__ __launch_bounds__(256) void cast_q8_x(const float* __restrict__ x,
                                                 const float* __restrict__ dinv,
                                                 const int* __restrict__ batch,
                                                 u16* __restrict__ q8,
                                                 float* __restrict__ qs,
                                                 int* __restrict__ gcnt) {
    int node = blockIdx.x * 4 + (threadIdx.x >> 6);
    if (node >= N_NODES) return;
    int lane = threadIdx.x & 63;
    float d = dinv[node];
    float2 v = *(const float2*)&x[(size_t)node * F0 + lane * 2];
    float f0 = v.x * d, f1 = v.y * d;
    float m = fmaxf(fabsf(f0), fabsf(f1));
    for (int s = 32; s > 0; s >>= 1) m = fmaxf(m, __shfl_xor(m, s, 64));
    float inv = (m > 0.f) ? 127.f / m : 0.f;
    int u0 = (int)rintf(f0 * inv) + 128, u1 = (int)rintf(f1 * inv) + 128;
    q8[(size_t)node * 64 + lane] = (u16)((u0 & 255) | ((u1 & 255) << 8));
    if (lane == 0) {
        qs[node] = m * (1.f / 127.f);
        atomicAdd(&gcnt[batch[node]], 1);
    }
}

// ---------------- weight transpose+cast (both layers, one launch) ----------------

__global__ void transpose_w2(const float* __restrict__ W1, const float* __restrict__ W2,
                             u16* __restrict__ W1t, u16* __restrict__ W2t) {
    int id = blockIdx.x * blockDim.x + threadIdx.x;
    if (id < F0 * F1) {
        int k = id / F1, n = id % F1;
        W1t[(size_t)n * F0 + k] = f2bf(W1[id]);
    } else {
        int id2 = id - F0 * F1;
        if (id2 < F1 * F1) {
            int k = id2 / F1, n = id2 % F1;
            W2t[(size_t)n * F1 + k] = f2bf(W2[id2]);
        }
    }
}

// ---------------- biased-u8 gather aggregation ----------------
// rows deq(j) = (u8 - 128)*qs[j] are h[j]*dinv[j];
// out[i] = bf16( dinv[i] * (sum_j deq(j) + deq(i)) ), via acc - 128*sum(scales)

template <int F>
__global__ __launch_bounds__(256) void aggregate_q8(const void* __restrict__ q8,
                                                    const float* __restrict__ qs,
                                                    const int* __restrict__ offs,
                                                    const int* __restrict__ csr,
                                                    const float* __restrict__ dinv,
                                                    u16* __restrict__ out) {
    constexpr int V = F / 64;
    int node = blockIdx.x * 4 + (threadIdx.x >> 6);
    if (node >= N_NODES) return;
    int lane = threadIdx.x & 63;
    float acc[V];
    float ssum;
    {
        float s = qs[node];
        ssum = s;
        if constexpr (V == 2) {
            uint32 q = (uint32)((const u16*)q8)[(size_t)node * 64 + lane];
            acc[0] = ub0(q) * s;
            acc[1] = ub1(q) * s;
        } else {
            uint32 q = ((const uint32*)q8)[(size_t)node * 64 + lane];
            acc[0] = ub0(q) * s;
            acc[1] = ub1(q) * s;
            acc[2] = ub2(q) * s;
            acc[3] = ub3(q) * s;
        }
    }
    int e0 = offs[node], e1 = offs[node + 1];
    for (int b = e0; b < e1; b += 64) {
        bool valid = (b + lane) < e1;
        int idx = valid ? csr[b + lane] : 0;
        float sv = valid ? qs[idx] : 0.f;
        int cnt = min(64, e1 - b);
        int t = 0;
        for (; t + 4 <= cnt; t += 4) {
            int j0 = __shfl(idx, t), j1 = __shfl(idx, t + 1);
            int j2 = __shfl(idx, t + 2), j3 = __shfl(idx, t + 3);
            float s0 = __shfl(sv, t), s1 = __shfl(sv, t + 1);
            float s2 = __shfl(sv, t + 2), s3 = __shfl(sv, t + 3);
            ssum += (s0 + s1) + (s2 + s3);
            if constexpr (V == 2) {
                uint32 a = (uint32)((const u16*)q8)[(size_t)j0 * 64 + lane];
                uint32 c = (uint32)((const u16*)q8)[(size_t)j1 * 64 + lane];
                uint32 d = (uint32)((const u16*)q8)[(size_t)j2 * 64 + lane];
                uint32 f = (uint32)((const u16*)q8)[(size_t)j3 * 64 + lane];
                acc[0] += ub0(a) * s0 + ub0(c) * s1 + ub0(d) * s2 + ub0(f) * s3;
                acc[1] += ub1(a) * s0 + ub1(c) * s1 + ub1(d) * s2 + ub1(f) * s3;
            } else {
                uint32 a = ((const uint32*)q8)[(size_t)j0 * 64 + lane];
                uint32 c = ((const uint32*)q8)[(size_t)j1 * 64 + lane];
                uint32 d = ((const uint32*)q8)[(size_t)j2 * 64 + lane];
                uint32 f = ((const uint32*)q8)[(size_t)j3 * 64 + lane];
                acc[0] += ub0(a) * s0 + ub0(c) * s1 + ub0(d) * s2 + ub0(f) * s3;
                acc[1] += ub1(a) * s0 + ub1(c) * s1 + ub1(d) * s2 + ub1(f) * s3;
                acc[2] += ub2(a) * s0 + ub2(c) * s1 + ub2(d) * s2 + ub2(f) * s3;
                acc[3] += ub3(a) * s0 + ub3(c) * s1 + ub3(d) * s2 + ub3(f) * s3;
            }
        }
        for (; t < cnt; ++t) {
            int j0 = __shfl(idx, t);
            float s0 = __shfl(sv, t);
            ssum += s0;
            if constexpr (V == 2) {
                uint32 a = (uint32)((const u16*)q8)[(size_t)j0 * 64 + lane];
                acc[0] += ub0(a) * s0;
                acc[1] += ub1(a) * s0;
            } else {
                uint32 a = ((const uint32*)q8)[(size_t)j0 * 64 + lane];
                acc[0] += ub0(a) * s0;
                acc[1] += ub1(a) * s0;
                acc[2] += ub2(a) * s0;
                acc[3] += ub3(a) * s0;
            }
        }
    }
    float di = dinv[node];
    float bias = 128.f * ssum;
    u16* orow = out + (size_t)node * F + lane * V;
    if constexpr (V == 2) {
        *(uint32*)orow = pack2((acc[0] - bias) * di, (acc[1] - bias) * di);
    } else {
        uint2 o;
        o.x = pack2((acc[0] - bias) * di, (acc[1] - bias) * di);
        o.y = pack2((acc[2] - bias) * di, (acc[3] - bias) * di);
        *(uint2*)orow = o;
    }
}

// ---------------- bf16 MFMA GEMM, BM=64 x BN=256 (full row per block) ----------------
// QUANT=true : epilogue = bias+relu, *dinv, row-absmax -> biased-u8 q8 + fp32 qs (replaces hs1+quantize_rows)
// QUANT=false: epilogue = bias+relu -> fused mean-pool atomics into gpool

template <int K, bool QUANT>
__global__ __launch_bounds__(256) void gemm_fused(const u16* __restrict__ A,
                                                  const u16* __restrict__ Bt,
                                                  const float* __restrict__ bias,
                                                  const float* __restrict__ dinv,
                                                  int M,
                                                  uint32* __restrict__ q8,
                                                  float* __restrict__ qs,
                                                  const int* __restrict__ batch,
                                                  float* __restrict__ gpool) {
    constexpr int BM = 64, BN = 256, BK = 64, BKP = 72;
    // staging: As 64x72x2=9216, Bs 256x72x2=36864 -> 46080 B
    // epilogue overlay: P[64][260] u16 = 33280 B, then rmax/batchl at +33280
    __shared__ __align__(16) char smem[46080];
    u16(*As)[BKP] = (u16(*)[BKP])smem;
    u16(*Bs)[BKP] = (u16(*)[BKP])(smem + BM * BKP * 2);
    int tid = threadIdx.x;
    int row0 = blockIdx.x * BM;
    int lane = tid & 63, wid = tid >> 6;
    int wn = wid * 64;
    int lr = lane & 15, lq = lane >> 4;

    f32x4 acc[4][4];
#pragma unroll
    for (int i = 0; i < 4; ++i)
#pragma unroll
        for (int j = 0; j < 4; ++j) acc[i][j] = (f32x4){0.f, 0.f, 0.f, 0.f};

    for (int k0 = 0; k0 < K; k0 += BK) {
        int c = (tid & 7) * 8;
#pragma unroll
        for (int p = 0; p < 2; ++p) {
            int r = (tid >> 3) + p * 32;
            u16x8 av = {0, 0, 0, 0, 0, 0, 0, 0};
            int gr = row0 + r;
            if (gr < M) av = *(const u16x8*)&A[(size_t)gr * K + k0 + c];
            *(u16x8*)&As[r][c] = av;
        }
#pragma unroll
        for (int p = 0; p < 8; ++p) {
            int r = (tid >> 3) + p * 32;
            *(u16x8*)&Bs[r][c] = *(const u16x8*)&Bt[(size_t)r * K + k0 + c];
        }
        __syncthreads();
#pragma unroll
        for (int kk = 0; kk < BK; kk += 32) {
            bf16x8 af[4], bfr[4];
#pragma unroll
            for (int i = 0; i < 4; ++i)
                af[i] = __builtin_bit_cast(bf16x8, *(const u16x8*)&As[i * 16 + lr][kk + lq * 8]);
#pragma unroll
            for (int j = 0; j < 4; ++j)
                bfr[j] = __builtin_bit_cast(bf16x8, *(const u16x8*)&Bs[wn + j * 16 + lr][kk + lq * 8]);
#pragma unroll
            for (int i = 0; i < 4; ++i)
#pragma unroll
                for (int j = 0; j < 4; ++j)
                    acc[i][j] = __builtin_amdgcn_mfma_f32_16x16x32_bf16(af[i], bfr[j], acc[i][j], 0, 0, 0);
        }
        __syncthreads();
    }

    // stage epilogue tile P[64][260] bf16 (overlays As/Bs)
    u16(*P)[260] = (u16(*)[260])smem;
#pragma unroll
    for (int i = 0; i < 4; ++i) {
#pragma unroll
        for (int j = 0; j < 4; ++j) {
            int cl = wn + j * 16 + lr;
            float bv = bias[cl];
#pragma unroll
            for (int r = 0; r < 4; ++r) {
                int rl = i * 16 + lq * 4 + r;
                int row = row0 + rl;
                float v = 0.f;
                if (row < M) {
                    v = fmaxf(acc[i][j][r] + bv, 0.f);
                    if constexpr (QUANT) v *= dinv[row];
                }
                P[rl][cl] = f2bf(v);
            }
        }
    }

    if constexpr (QUANT) {
        float* rmax = (float*)(smem + 33280);  // [4][64]
        __syncthreads();
        int row = tid & 63, q = tid >> 6;
        float m = 0.f;
#pragma unroll 8
        for (int i = 0; i < 64; ++i) m = fmaxf(m, b16f(P[row][q * 64 + i]));  // post-relu >= 0
        rmax[q * 64 + row] = m;
        __syncthreads();
        m = fmaxf(fmaxf(rmax[row], rmax[64 + row]), fmaxf(rmax[128 + row], rmax[192 + row]));
        int gr = row0 + row;
        if (gr < M) {
            float inv = (m > 0.f) ? 127.f / m : 0.f;
#pragma unroll
            for (int d = 0; d < 16; d += 4) {
                uint32 dw[4];
#pragma unroll
                for (int e = 0; e < 4; ++e) {
                    int cb = q * 64 + (d + e) * 4;
                    uint32 v0 = (uint32)((int)rintf(b16f(P[row][cb + 0]) * inv) + 128);
                    uint32 v1 = (uint32)((int)rintf(b16f(P[row][cb + 1]) * inv) + 128);
                    uint32 v2 = (uint32)((int)rintf(b16f(P[row][cb + 2]) * inv) + 128);
                    uint32 v3 = (uint32)((int)rintf(b16f(P[row][cb + 3]) * inv) + 128);
                    dw[e] = v0 | (v1 << 8) | (v2 << 16) | (v3 << 24);
                }
                *(uint4*)&q8[(size_t)gr * 64 + q * 16 + d] = make_uint4(dw[0], dw[1], dw[2], dw[3]);
            }
            if (q == 0) qs[gr] = m * (1.f / 127.f);
        }
    } else {
        int* batchl = (int*)(smem + 33280);  // [64]
        if (tid < BM) {
            int row = row0 + tid;
            batchl[tid] = batch[row < M ? row : (M - 1)];
        }
        __syncthreads();
        int c = tid;  // one column per thread
        int nrows = min(BM, M - row0);
        int cur = batchl[0];
        float sum = 0.f;
        for (int r = 0; r < nrows; ++r) {
            int gb = batchl[r];
            float v = b16f(P[r][c]);
            if (gb != cur) {
                atomicAdd(&gpool[(size_t)cur * BN + c], sum);
                sum = 0.f;
                cur = gb;
            }
            sum += v;
        }
        atomicAdd(&gpool[(size_t)cur * BN + c], sum);
    }
}

// ---------------- classifier + log_softmax ----------------

__global__ void classify(const float* __restrict__ gpool, const int* __restrict__ gcnt,
                         const float* __restrict__ Wc, const float* __restrict__ bc,
                         float* __restrict__ out) {
    int gr = blockIdx.x;
    int c = threadIdx.x;  // 0..63, single wave
    __shared__ float gl[F1];
    float inv = 1.f / fmaxf((float)gcnt[gr], 1.f);
    for (int k = c; k < F1; k += 64) gl[k] = gpool[(size_t)gr * F1 + k] * inv;
    __syncthreads();
    float acc = bc[c];
    for (int k = 0; k < F1; ++k) acc += gl[k] * Wc[k * NCLS + c];
    float m = acc;
    for (int s = 32; s > 0; s >>= 1) m = fmaxf(m, __shfl_xor(m, s, 64));
    float ex = __expf(acc - m);
    float sum = ex;
    for (int s = 32; s > 0; s >>= 1) sum += __shfl_xor(sum, s, 64);
    out[(size_t)gr * NCLS + c] = acc - m - __logf(sum);
}

// ---------------- launch ----------------

extern "C" void kernel_launch(void* const* d_in, const int* in_sizes, int n_in,
                              void* d_out, int out_size, void* d_ws, size_t ws_size,
                              hipStream_t stream) {
    const float* x = (const float*)d_in[0];
    const int* ei = (const int*)d_in[1];
    const int* batch = (const int*)d_in[2];
    const float* W1 = (const float*)d_in[3];
    const float* b1 = (const float*)d_in[4];
    const float* W2 = (const float*)d_in[5];
    const float* b2 = (const float*)d_in[6];
    const float* Wc = (const float*)d_in[7];
    const float* bc = (const float*)d_in[8];
    float* out = (float*)d_out;
    const int* src = ei;
    const int* dst = ei + N_EDGES;

    char* w = (char*)d_ws;
    auto take = [&](size_t n) { char* p = w; w += (n + 255) & ~(size_t)255; return p; };
    float* dinv = (float*)take((size_t)N_NODES * 4);
    int* offs = (int*)take((size_t)(N_NODES + 1) * 4);
    int* hist = (int*)take((size_t)FLATN * 4);
    int* histoff = (int*)take((size_t)(FLATN + 1) * 4);
    int* bsum = (int*)take((size_t)1024 * 4);
    int* gcnt = (int*)take((size_t)N_GRAPHS * 4);
    uint32* pairs = (uint32*)take((size_t)N_EDGES * 4);
    int* csr = (int*)take((size_t)N_EDGES * 4);
    u16* q8x = (u16*)take((size_t)N_NODES * 64 * 2);        // biased u8 x*dinv rows (128 B/row)
    float* qsx = (float*)take((size_t)N_NODES * 4);
    uint32* q8h = (uint32*)take((size_t)N_NODES * 64 * 4);  // biased u8 h1*dinv rows (256 B/row)
    float* qsh = (float*)take((size_t)N_NODES * 4);
    u16* aggx = (u16*)take((size_t)N_NODES * F0 * 2);       // bf16
    u16* agg1 = (u16*)take((size_t)N_NODES * F1 * 2);       // bf16
    u16* W1t = (u16*)take((size_t)F0 * F1 * 2);
    u16* W2t = (u16*)take((size_t)F1 * F1 * 2);
    float* gpool = (float*)take((size_t)N_GRAPHS * F1 * 4);

    hipMemsetAsync(gcnt, 0, (size_t)N_GRAPHS * 4, stream);
    hipMemsetAsync(gpool, 0, (size_t)N_GRAPHS * F1 * 4, stream);

    // CSR build: hist -> scan -> bin -> per-bucket finalize (deg/dinv/offs/csr)
    hist_pass<<<NCHUNK, 256, 0, stream>>>(dst, hist);
    {
        int nb = (FLATN + SCAN_B - 1) / SCAN_B;  // 75
        scan_partial<<<nb, SCAN_B, 0, stream>>>(hist, FLATN, bsum);
        scan_bsum<<<1, SCAN_B, 0, stream>>>(bsum, nb);
        scan_final<<<nb, SCAN_B, 0, stream>>>(hist, FLATN, bsum, histoff);
    }
    bin_pairs<<<NCHUNK, 256, 0, stream>>>(src, dst, histoff, pairs);
    bucket_csr<<<NB, 256, 0, stream>>>(pairs, histoff, offs, csr, dinv);

    // weight prep + x quantize (scaled by dinv; also counts batch)
    transpose_w2<<<(F0 * F1 + F1 * F1 + 255) / 256, 256, 0, stream>>>(W1, W2, W1t, W2t);
    cast_q8_x<<<(N_NODES + 3) / 4, 256, 0, stream>>>(x, dinv, batch, q8x, qsx, gcnt);

    int mblocks = (N_NODES + 63) / 64;  // 1563

    // conv1: u8 gather-aggregate -> bf16, MFMA GEMM (+b1, relu, *dinv) with fused quantize -> q8h
    aggregate_q8<F0><<<(N_NODES + 3) / 4, 256, 0, stream>>>(q8x, qsx, offs, csr, dinv, aggx);
    gemm_fused<F0, true><<<mblocks, 256, 0, stream>>>(aggx, W1t, b1, dinv, N_NODES,
                                                      q8h, qsh, nullptr, nullptr);

    // conv2: u8 gather-aggregate -> bf16, MFMA GEMM (+b2, relu) with fused mean-pool
    aggregate_q8<F1><<<(N_NODES + 3) / 4, 256, 0, stream>>>(q8h, qsh, offs, csr, dinv, agg1);
    gemm_fused<F1, false><<<mblocks, 256, 0, stream>>>(agg1, W2t, b2, dinv, N_NODES,
                                                       nullptr, nullptr, batch, gpool);

    // classifier + log_softmax
    classify<<<N_GRAPHS, 64, 0, stream>>>(gpool, gcnt, Wc, bc, out);
}

// Round 7
// 427.578 us; speedup vs baseline: 2.4760x; 1.0769x over previous
//
#include <hip/hip_runtime.h>
#include <hip/hip_bf16.h>

#define N_NODES 100000
#define N_EDGES 1600000
#define N_GRAPHS 2048
#define F0 128
#define F1 256
#define NCLS 64

// bucketed CSR build
#define BSHIFT 9
#define BNODES 512
#define NB 196
#define EPB 4096
#define NCHUNK 391
#define FLATN (NB * NCHUNK)

typedef unsigned int uint32;
typedef unsigned short u16;
typedef u16 u16x8 __attribute__((ext_vector_type(8)));
typedef __bf16 bf16x8 __attribute__((ext_vector_type(8)));
typedef float f32x4 __attribute__((ext_vector_type(4)));

__device__ __forceinline__ float blo(uint32 v) { return __builtin_bit_cast(float, v << 16); }
__device__ __forceinline__ float bhi(uint32 v) { return __builtin_bit_cast(float, v & 0xffff0000u); }
__device__ __forceinline__ float b16f(u16 v) { return __builtin_bit_cast(float, (uint32)v << 16); }
__device__ __forceinline__ u16 f2bf(float f) {
    uint32 u = __builtin_bit_cast(uint32, f);
    u += 0x7fffu + ((u >> 16) & 1u);  // RNE
    return (u16)(u >> 16);
}
__device__ __forceinline__ uint32 pack2(float a, float b) {
    return (uint32)f2bf(a) | ((uint32)f2bf(b) << 16);
}
// biased-u8 dequant helpers: compiler emits v_cvt_f32_ubyte0..3
__device__ __forceinline__ float ub0(uint32 u) { return (float)(u & 255u); }
__device__ __forceinline__ float ub1(uint32 u) { return (float)((u >> 8) & 255u); }
__device__ __forceinline__ float ub2(uint32 u) { return (float)((u >> 16) & 255u); }
__device__ __forceinline__ float ub3(uint32 u) { return (float)(u >> 24); }

// async global->LDS, 16 B per lane, deposit at wave-uniform base + lane*16
#define GLOAD_LDS16(g, l)                                                                  \
    __builtin_amdgcn_global_load_lds((const __attribute__((address_space(1))) void*)(g),   \
                                     (__attribute__((address_space(3))) void*)(l), 16, 0, 0)

// ---------------- scans ----------------
#define SCAN_B 1024

__global__ void scan_partial(const int* __restrict__ in, int n, int* __restrict__ bsum) {
    __shared__ int lds[SCAN_B];
    int i = blockIdx.x * SCAN_B + threadIdx.x;
    lds[threadIdx.x] = (i < n) ? in[i] : 0;
    __syncthreads();
    for (int s = SCAN_B / 2; s > 0; s >>= 1) {
        if (threadIdx.x < s) lds[threadIdx.x] += lds[threadIdx.x + s];
        __syncthreads();
    }
    if (threadIdx.x == 0) bsum[blockIdx.x] = lds[0];
}

// scan_final with inlined block-prefix of partials (nb <= 128); replaces scan_bsum+scan_final
__global__ void scan_final(const int* __restrict__ in, int n, const int* __restrict__ bsum,
                           int nb, int* __restrict__ out) {
    __shared__ int lds[SCAN_B];
    __shared__ int bpre[128];
    if (threadIdx.x < 128) bpre[threadIdx.x] = (threadIdx.x < nb) ? bsum[threadIdx.x] : 0;
    __syncthreads();
    for (int s = 1; s < 128; s <<= 1) {
        int v = (threadIdx.x < 128 && threadIdx.x >= s) ? bpre[threadIdx.x - s] : 0;
        __syncthreads();
        if (threadIdx.x < 128) bpre[threadIdx.x] += v;
        __syncthreads();
    }
    int base = (blockIdx.x > 0) ? bpre[blockIdx.x - 1] : 0;  // exclusive block offset
    int i = blockIdx.x * SCAN_B + threadIdx.x;
    int v = (i < n) ? in[i] : 0;
    lds[threadIdx.x] = v;
    __syncthreads();
    for (int s = 1; s < SCAN_B; s <<= 1) {
        int t = (threadIdx.x >= s) ? lds[threadIdx.x - s] : 0;
        __syncthreads();
        lds[threadIdx.x] += t;
        __syncthreads();
    }
    if (i < n) out[i + 1] = lds[threadIdx.x] + base;
    if (i == 0) out[0] = 0;
}

// ---------------- bucketed CSR build ----------------

__global__ __launch_bounds__(256) void hist_pass(const int* __restrict__ dst,
                                                 int* __restrict__ hist) {
    __shared__ int lh[NB];
    int t = threadIdx.x, blk = blockIdx.x;
    if (t < NB) lh[t] = 0;
    __syncthreads();
#pragma unroll
    for (int k = 0; k < EPB / 256; ++k) {
        int e = blk * EPB + k * 256 + t;
        if (e < N_EDGES) atomicAdd(&lh[dst[e] >> BSHIFT], 1);
    }
    __syncthreads();
    if (t < NB) hist[t * NCHUNK + blk] = lh[t];
}

__global__ __launch_bounds__(256) void bin_pairs(const int* __restrict__ src,
                                                 const int* __restrict__ dst,
                                                 const int* __restrict__ histoff,
                                                 uint32* __restrict__ pairs) {
    __shared__ int lbase[NB];
    __shared__ int lcur[NB];
    int t = threadIdx.x, blk = blockIdx.x;
    if (t < NB) {
        lbase[t] = histoff[t * NCHUNK + blk];
        lcur[t] = 0;
    }
    __syncthreads();
#pragma unroll
    for (int k = 0; k < EPB / 256; ++k) {
        int e = blk * EPB + k * 256 + t;
        if (e < N_EDGES) {
            int d = dst[e], s = src[e];
            int b = d >> BSHIFT;
            int r = atomicAdd(&lcur[b], 1);
            pairs[lbase[b] + r] = (uint32)(d & (BNODES - 1)) | ((uint32)s << BSHIFT);
        }
    }
}

#define PCAP 16384  // LDS pairs cache (mean bucket ~8163, ~90 sigma headroom)

__global__ __launch_bounds__(256) void bucket_csr(const uint32* __restrict__ pairs,
                                                  const int* __restrict__ histoff,
                                                  int* __restrict__ offs,
                                                  int* __restrict__ csr,
                                                  float* __restrict__ dinv) {
    __shared__ uint32 lp[PCAP];
    __shared__ int lcnt[BNODES];
    __shared__ int lcur[BNODES];
    __shared__ int psum[256];
    int t = threadIdx.x, b = blockIdx.x;
    int n0 = b << BSHIFT;
    int nn = min(BNODES, N_NODES - n0);
    lcnt[t] = 0;
    lcnt[t + 256] = 0;
    __syncthreads();
    int ebase = histoff[b * NCHUNK];
    int eend = (b == NB - 1) ? N_EDGES : histoff[(b + 1) * NCHUNK];
    for (int i = ebase + t; i < eend; i += 256) {
        uint32 p = pairs[i];
        int li = i - ebase;
        if (li < PCAP) lp[li] = p;
        atomicAdd(&lcnt[p & (BNODES - 1)], 1);
    }
    __syncthreads();
    int c0 = lcnt[2 * t], c1 = lcnt[2 * t + 1];
    if (2 * t < nn) dinv[n0 + 2 * t] = rsqrtf((float)(c0 + 1));
    if (2 * t + 1 < nn) dinv[n0 + 2 * t + 1] = rsqrtf((float)(c1 + 1));
    psum[t] = c0 + c1;
    __syncthreads();
    for (int s = 1; s < 256; s <<= 1) {
        int v = (t >= s) ? psum[t - s] : 0;
        __syncthreads();
        psum[t] += v;
        __syncthreads();
    }
    int ep = psum[t] - (c0 + c1);
    lcur[2 * t] = ep;
    lcur[2 * t + 1] = ep + c0;
    if (2 * t < nn) offs[n0 + 2 * t] = ebase + ep;
    if (2 * t + 1 < nn) offs[n0 + 2 * t + 1] = ebase + ep + c0;
    if (b == NB - 1 && t == 0) offs[N_NODES] = N_EDGES;
    __syncthreads();
    for (int i = ebase + t; i < eend; i += 256) {
        int li = i - ebase;
        uint32 p = (li < PCAP) ? lp[li] : pairs[i];
        int r = atomicAdd(&lcur[p & (BNODES - 1)], 1);
        csr[ebase + r] = (int)(p >> BSHIFT);
    }
}

// ---------------- quantize x: biased u8 row + fp32 scale; fuses count_batch ----------------

__global__ __launch_bounds__(256) void cast_q8_x(const float* __restrict__ x,
                                                 const float* __restrict__ dinv,
                                                 const int* __restrict__ batch,
                                                 u16* __restrict__ q8,
                                                 float* __restrict__ qs,
                                                 int* __restrict__ gcnt) {
    int node = blockIdx.x * 4 + (threadIdx.x >> 6);
    if (node >= N_NODES) return;
    int lane = threadIdx.x & 63;
    float d = dinv[node];
    float2 v = *(const float2*)&x[(size_t)node * F0 + lane * 2];
    float f0 = v.x * d, f1 = v.y * d;
    float m = fmaxf(fabsf(f0), fabsf(f1));
    for (int s = 32; s > 0; s >>= 1) m = fmaxf(m, __shfl_xor(m, s, 64));
    float inv = (m > 0.f) ? 127.f / m : 0.f;
    int u0 = (int)rintf(f0 * inv) + 128, u1 = (int)rintf(f1 * inv) + 128;
    q8[(size_t)node * 64 + lane] = (u16)((u0 & 255) | ((u1 & 255) << 8));
    if (lane == 0) {
        qs[node] = m * (1.f / 127.f);
        atomicAdd(&gcnt[batch[node]], 1);
    }
}

// ---------------- weight transpose+cast (both layers, one launch) ----------------

__global__ void transpose_w2(const float* __restrict__ W1, const float* __restrict__ W2,
                             u16* __restrict__ W1t, u16* __restrict__ W2t) {
    int id = blockIdx.x * blockDim.x + threadIdx.x;
    if (id < F0 * F1) {
        int k = id / F1, n = id % F1;
        W1t[(size_t)n * F0 + k] = f2bf(W1[id]);
    } else {
        int id2 = id - F0 * F1;
        if (id2 < F1 * F1) {
            int k = id2 / F1, n = id2 % F1;
            W2t[(size_t)n * F1 + k] = f2bf(W2[id2]);
        }
    }
}

// ---------------- biased-u8 gather aggregation ----------------
// rows deq(j) = (u8 - 128)*qs[j] are h[j]*dinv[j];
// out[i] = bf16( dinv[i] * (sum_j deq(j) + deq(i)) ), via acc - 128*sum(scales)

template <int F>
__global__ __launch_bounds__(256) void aggregate_q8(const void* __restrict__ q8,
                                                    const float* __restrict__ qs,
                                                    const int* __restrict__ offs,
                                                    const int* __restrict__ csr,
                                                    const float* __restrict__ dinv,
                                                    u16* __restrict__ out) {
    constexpr int V = F / 64;
    int node = blockIdx.x * 4 + (threadIdx.x >> 6);
    if (node >= N_NODES) return;
    int lane = threadIdx.x & 63;
    float acc[V];
    float ssum;
    {
        float s = qs[node];
        ssum = s;
        if constexpr (V == 2) {
            uint32 q = (uint32)((const u16*)q8)[(size_t)node * 64 + lane];
            acc[0] = ub0(q) * s;
            acc[1] = ub1(q) * s;
        } else {
            uint32 q = ((const uint32*)q8)[(size_t)node * 64 + lane];
            acc[0] = ub0(q) * s;
            acc[1] = ub1(q) * s;
            acc[2] = ub2(q) * s;
            acc[3] = ub3(q) * s;
        }
    }
    int e0 = offs[node], e1 = offs[node + 1];
    for (int b = e0; b < e1; b += 64) {
        bool valid = (b + lane) < e1;
        int idx = valid ? csr[b + lane] : 0;
        float sv = valid ? qs[idx] : 0.f;
        int cnt = min(64, e1 - b);
        int t = 0;
        for (; t + 4 <= cnt; t += 4) {
            int j0 = __shfl(idx, t), j1 = __shfl(idx, t + 1);
            int j2 = __shfl(idx, t + 2), j3 = __shfl(idx, t + 3);
            float s0 = __shfl(sv, t), s1 = __shfl(sv, t + 1);
            float s2 = __shfl(sv, t + 2), s3 = __shfl(sv, t + 3);
            ssum += (s0 + s1) + (s2 + s3);
            if constexpr (V == 2) {
                uint32 a = (uint32)((const u16*)q8)[(size_t)j0 * 64 + lane];
                uint32 c = (uint32)((const u16*)q8)[(size_t)j1 * 64 + lane];
                uint32 d = (uint32)((const u16*)q8)[(size_t)j2 * 64 + lane];
                uint32 f = (uint32)((const u16*)q8)[(size_t)j3 * 64 + lane];
                acc[0] += ub0(a) * s0 + ub0(c) * s1 + ub0(d) * s2 + ub0(f) * s3;
                acc[1] += ub1(a) * s0 + ub1(c) * s1 + ub1(d) * s2 + ub1(f) * s3;
            } else {
                uint32 a = ((const uint32*)q8)[(size_t)j0 * 64 + lane];
                uint32 c = ((const uint32*)q8)[(size_t)j1 * 64 + lane];
                uint32 d = ((const uint32*)q8)[(size_t)j2 * 64 + lane];
                uint32 f = ((const uint32*)q8)[(size_t)j3 * 64 + lane];
                acc[0] += ub0(a) * s0 + ub0(c) * s1 + ub0(d) * s2 + ub0(f) * s3;
                acc[1] += ub1(a) * s0 + ub1(c) * s1 + ub1(d) * s2 + ub1(f) * s3;
                acc[2] += ub2(a) * s0 + ub2(c) * s1 + ub2(d) * s2 + ub2(f) * s3;
                acc[3] += ub3(a) * s0 + ub3(c) * s1 + ub3(d) * s2 + ub3(f) * s3;
            }
        }
        for (; t < cnt; ++t) {
            int j0 = __shfl(idx, t);
            float s0 = __shfl(sv, t);
            ssum += s0;
            if constexpr (V == 2) {
                uint32 a = (uint32)((const u16*)q8)[(size_t)j0 * 64 + lane];
                acc[0] += ub0(a) * s0;
                acc[1] += ub1(a) * s0;
            } else {
                uint32 a = ((const uint32*)q8)[(size_t)j0 * 64 + lane];
                acc[0] += ub0(a) * s0;
                acc[1] += ub1(a) * s0;
                acc[2] += ub2(a) * s0;
                acc[3] += ub3(a) * s0;
            }
        }
    }
    float di = dinv[node];
    float bias = 128.f * ssum;
    u16* orow = out + (size_t)node * F + lane * V;
    if constexpr (V == 2) {
        *(uint32*)orow = pack2((acc[0] - bias) * di, (acc[1] - bias) * di);
    } else {
        uint2 o;
        o.x = pack2((acc[0] - bias) * di, (acc[1] - bias) * di);
        o.y = pack2((acc[2] - bias) * di, (acc[3] - bias) * di);
        *(uint2*)orow = o;
    }
}

// ---------------- bf16 MFMA GEMM, BM=64 x BN=256, m97-style global_load_lds staging ----------------
// A rows are read unguarded (caller pads A by >=64 rows); rows >= M produce discarded outputs.
// QUANT=true : epilogue = bias+relu, *dinv, row-absmax -> biased-u8 q8 + fp32 qs
// QUANT=false: epilogue = bias+relu -> fused mean-pool atomics into gpool

template <int K, bool QUANT>
__global__ __launch_bounds__(256) void gemm_fused(const u16* __restrict__ A,
                                                  const u16* __restrict__ Bt,
                                                  const float* __restrict__ bias,
                                                  const float* __restrict__ dinv,
                                                  int M,
                                                  uint32* __restrict__ q8,
                                                  float* __restrict__ qs,
                                                  const int* __restrict__ batch,
                                                  float* __restrict__ gpool) {
    constexpr int BM = 64, BN = 256, BK = 64;
    // packed tiles: As 64x64 u16 (8 KB) + Bs 256x64 u16 (32 KB) = 40960 B
    // epilogue overlay: P[64][260] u16 (33280 B) + rmax/batchl at +33280
    __shared__ __align__(16) char smem[40960];
    u16* As = (u16*)smem;
    u16* Bs = (u16*)smem + BM * BK;
    int tid = threadIdx.x;
    int lane = tid & 63;
    int wid = __builtin_amdgcn_readfirstlane(tid >> 6);
    int row0 = blockIdx.x * BM;
    int lr = lane & 15, lq = lane >> 4;
    int wn = wid * 64;
    int srow = lane >> 3;         // 0..7: row within 8-row group
    int schunk = (lane & 7) * 8;  // u16 offset within row

    f32x4 acc[4][4];
#pragma unroll
    for (int i = 0; i < 4; ++i)
#pragma unroll
        for (int j = 0; j < 4; ++j) acc[i][j] = (f32x4){0.f, 0.f, 0.f, 0.f};

    for (int k0 = 0; k0 < K; k0 += BK) {
        // A: 64 rows, each wave stages 16 rows (2 DMA instrs)
#pragma unroll
        for (int p = 0; p < 2; ++p) {
            int r0 = wid * 16 + p * 8;
            const u16* g = A + (size_t)(row0 + r0 + srow) * K + k0 + schunk;
            GLOAD_LDS16(g, As + r0 * BK);
        }
        // B: 256 rows, each wave stages 64 rows (8 DMA instrs)
#pragma unroll
        for (int p = 0; p < 8; ++p) {
            int r0 = wid * 64 + p * 8;
            const u16* g = Bt + (size_t)(r0 + srow) * K + k0 + schunk;
            GLOAD_LDS16(g, Bs + r0 * BK);
        }
        __syncthreads();
#pragma unroll
        for (int kk = 0; kk < BK; kk += 32) {
            bf16x8 af[4], bfr[4];
#pragma unroll
            for (int i = 0; i < 4; ++i)
                af[i] = __builtin_bit_cast(bf16x8, *(const u16x8*)&As[(i * 16 + lr) * BK + kk + lq * 8]);
#pragma unroll
            for (int j = 0; j < 4; ++j)
                bfr[j] = __builtin_bit_cast(bf16x8, *(const u16x8*)&Bs[(wn + j * 16 + lr) * BK + kk + lq * 8]);
#pragma unroll
            for (int i = 0; i < 4; ++i)
#pragma unroll
                for (int j = 0; j < 4; ++j)
                    acc[i][j] = __builtin_amdgcn_mfma_f32_16x16x32_bf16(af[i], bfr[j], acc[i][j], 0, 0, 0);
        }
        __syncthreads();
    }

    // stage epilogue tile P[64][260] bf16 (overlays As/Bs)
    u16(*P)[260] = (u16(*)[260])smem;
#pragma unroll
    for (int i = 0; i < 4; ++i) {
#pragma unroll
        for (int j = 0; j < 4; ++j) {
            int cl = wn + j * 16 + lr;
            float bv = bias[cl];
#pragma unroll
            for (int r = 0; r < 4; ++r) {
                int rl = i * 16 + lq * 4 + r;
                int row = row0 + rl;
                float v = 0.f;
                if (row < M) {
                    v = fmaxf(acc[i][j][r] + bv, 0.f);
                    if constexpr (QUANT) v *= dinv[row];
                }
                P[rl][cl] = f2bf(v);
            }
        }
    }

    if constexpr (QUANT) {
        float* rmax = (float*)(smem + 33280);  // [4][64]
        __syncthreads();
        int row = tid & 63, q = tid >> 6;
        float m = 0.f;
#pragma unroll 8
        for (int i = 0; i < 64; ++i) m = fmaxf(m, b16f(P[row][q * 64 + i]));  // post-relu >= 0
        rmax[q * 64 + row] = m;
        __syncthreads();
        m = fmaxf(fmaxf(rmax[row], rmax[64 + row]), fmaxf(rmax[128 + row], rmax[192 + row]));
        int gr = row0 + row;
        if (gr < M) {
            float inv = (m > 0.f) ? 127.f / m : 0.f;
#pragma unroll
            for (int d = 0; d < 16; d += 4) {
                uint32 dw[4];
#pragma unroll
                for (int e = 0; e < 4; ++e) {
                    int cb = q * 64 + (d + e) * 4;
                    uint32 v0 = (uint32)((int)rintf(b16f(P[row][cb + 0]) * inv) + 128);
                    uint32 v1 = (uint32)((int)rintf(b16f(P[row][cb + 1]) * inv) + 128);
                    uint32 v2 = (uint32)((int)rintf(b16f(P[row][cb + 2]) * inv) + 128);
                    uint32 v3 = (uint32)((int)rintf(b16f(P[row][cb + 3]) * inv) + 128);
                    dw[e] = v0 | (v1 << 8) | (v2 << 16) | (v3 << 24);
                }
                *(uint4*)&q8[(size_t)gr * 64 + q * 16 + d] = make_uint4(dw[0], dw[1], dw[2], dw[3]);
            }
            if (q == 0) qs[gr] = m * (1.f / 127.f);
        }
    } else {
        int* batchl = (int*)(smem + 33280);  // [64]
        if (tid < BM) {
            int row = row0 + tid;
            batchl[tid] = batch[row < M ? row : (M - 1)];
        }
        __syncthreads();
        int c = tid;  // one column per thread
        int nrows = min(BM, M - row0);
        int cur = batchl[0];
        float sum = 0.f;
        for (int r = 0; r < nrows; ++r) {
            int gb = batchl[r];
            float v = b16f(P[r][c]);
            if (gb != cur) {
                atomicAdd(&gpool[(size_t)cur * BN + c], sum);
                sum = 0.f;
                cur = gb;
            }
            sum += v;
        }
        atomicAdd(&gpool[(size_t)cur * BN + c], sum);
    }
}

// ---------------- classifier + log_softmax ----------------

__global__ void classify(const float* __restrict__ gpool, const int* __restrict__ gcnt,
                         const float* __restrict__ Wc, const float* __restrict__ bc,
                         float* __restrict__ out) {
    int gr = blockIdx.x;
    int c = threadIdx.x;  // 0..63, single wave
    __shared__ float gl[F1];
    float inv = 1.f / fmaxf((float)gcnt[gr], 1.f);
    for (int k = c; k < F1; k += 64) gl[k] = gpool[(size_t)gr * F1 + k] * inv;
    __syncthreads();
    float acc = bc[c];
    for (int k = 0; k < F1; ++k) acc += gl[k] * Wc[k * NCLS + c];
    float m = acc;
    for (int s = 32; s > 0; s >>= 1) m = fmaxf(m, __shfl_xor(m, s, 64));
    float ex = __expf(acc - m);
    float sum = ex;
    for (int s = 32; s > 0; s >>= 1) sum += __shfl_xor(sum, s, 64);
    out[(size_t)gr * NCLS + c] = acc - m - __logf(sum);
}

// ---------------- launch ----------------

extern "C" void kernel_launch(void* const* d_in, const int* in_sizes, int n_in,
                              void* d_out, int out_size, void* d_ws, size_t ws_size,
                              hipStream_t stream) {
    const float* x = (const float*)d_in[0];
    const int* ei = (const int*)d_in[1];
    const int* batch = (const int*)d_in[2];
    const float* W1 = (const float*)d_in[3];
    const float* b1 = (const float*)d_in[4];
    const float* W2 = (const float*)d_in[5];
    const float* b2 = (const float*)d_in[6];
    const float* Wc = (const float*)d_in[7];
    const float* bc = (const float*)d_in[8];
    float* out = (float*)d_out;
    const int* src = ei;
    const int* dst = ei + N_EDGES;

    char* w = (char*)d_ws;
    auto take = [&](size_t n) { char* p = w; w += (n + 255) & ~(size_t)255; return p; };
    float* dinv = (float*)take((size_t)N_NODES * 4);
    int* offs = (int*)take((size_t)(N_NODES + 1) * 4);
    int* hist = (int*)take((size_t)FLATN * 4);
    int* histoff = (int*)take((size_t)(FLATN + 1) * 4);
    int* bsum = (int*)take((size_t)1024 * 4);
    int* gcnt = (int*)take((size_t)N_GRAPHS * 4);
    uint32* pairs = (uint32*)take((size_t)N_EDGES * 4);
    int* csr = (int*)take((size_t)N_EDGES * 4);
    u16* q8x = (u16*)take((size_t)N_NODES * 64 * 2);        // biased u8 x*dinv rows (128 B/row)
    float* qsx = (float*)take((size_t)N_NODES * 4);
    uint32* q8h = (uint32*)take((size_t)N_NODES * 64 * 4);  // biased u8 h1*dinv rows (256 B/row)
    float* qsh = (float*)take((size_t)N_NODES * 4);
    u16* aggx = (u16*)take((size_t)(N_NODES + 64) * F0 * 2);  // bf16, +64 rows GEMM overread pad
    u16* agg1 = (u16*)take((size_t)(N_NODES + 64) * F1 * 2);  // bf16, +64 rows pad
    u16* W1t = (u16*)take((size_t)F0 * F1 * 2);
    u16* W2t = (u16*)take((size_t)F1 * F1 * 2);
    float* gpool = (float*)take((size_t)N_GRAPHS * F1 * 4);

    hipMemsetAsync(gcnt, 0, (size_t)N_GRAPHS * 4, stream);
    hipMemsetAsync(gpool, 0, (size_t)N_GRAPHS * F1 * 4, stream);

    // CSR build: hist -> scan (2 launches) -> bin -> per-bucket finalize (deg/dinv/offs/csr)
    hist_pass<<<NCHUNK, 256, 0, stream>>>(dst, hist);
    {
        int nb = (FLATN + SCAN_B - 1) / SCAN_B;  // 75
        scan_partial<<<nb, SCAN_B, 0, stream>>>(hist, FLATN, bsum);
        scan_final<<<nb, SCAN_B, 0, stream>>>(hist, FLATN, bsum, nb, histoff);
    }
    bin_pairs<<<NCHUNK, 256, 0, stream>>>(src, dst, histoff, pairs);
    bucket_csr<<<NB, 256, 0, stream>>>(pairs, histoff, offs, csr, dinv);

    // weight prep + x quantize (scaled by dinv; also counts batch)
    transpose_w2<<<(F0 * F1 + F1 * F1 + 255) / 256, 256, 0, stream>>>(W1, W2, W1t, W2t);
    cast_q8_x<<<(N_NODES + 3) / 4, 256, 0, stream>>>(x, dinv, batch, q8x, qsx, gcnt);

    int mblocks = (N_NODES + 63) / 64;  // 1563

    // conv1: u8 gather-aggregate -> bf16, MFMA GEMM (+b1, relu, *dinv) with fused quantize -> q8h
    aggregate_q8<F0><<<(N_NODES + 3) / 4, 256, 0, stream>>>(q8x, qsx, offs, csr, dinv, aggx);
    gemm_fused<F0, true><<<mblocks, 256, 0, stream>>>(aggx, W1t, b1, dinv, N_NODES,
                                                      q8h, qsh, nullptr, nullptr);

    // conv2: u8 gather-aggregate -> bf16, MFMA GEMM (+b2, relu) with fused mean-pool
    aggregate_q8<F1><<<(N_NODES + 3) / 4, 256, 0, stream>>>(q8h, qsh, offs, csr, dinv, agg1);
    gemm_fused<F1, false><<<mblocks, 256, 0, stream>>>(agg1, W2t, b2, dinv, N_NODES,
                                                       nullptr, nullptr, batch, gpool);

    // classifier + log_softmax
    classify<<<N_GRAPHS, 64, 0, stream>>>(gpool, gcnt, Wc, bc, out);
}